// Round 1
// baseline (4260.425 us; speedup 1.0000x reference)
//
#include <hip/hip_runtime.h>
#include <math.h>

#define D_DIM 512
#define H_DIM 2048
#define NEXP  8
#define BT    64     // tokens per tile
#define KC    64     // k-chunk (layer1)
#define HC    64     // h-chunk
#define TPB   512    // threads per block

__device__ __forceinline__ float gelu_exact(float v) {
    return 0.5f * v * (1.0f + erff(v * 0.70710678118654752440f));
}

// ---------------- router: logits -> top2 -> softmax -> expert lists ----------
__global__ void router_kernel(const float* __restrict__ x,
                              const float* __restrict__ Wr,
                              float* __restrict__ gate_w,
                              int* __restrict__ lists,
                              int* __restrict__ counts,
                              int ntok) {
    int wid  = (blockIdx.x * blockDim.x + threadIdx.x) >> 6;  // one wave per token
    int lane = threadIdx.x & 63;
    if (wid >= ntok) return;
    const float* xr = x + (size_t)wid * D_DIM;
    float acc[NEXP];
#pragma unroll
    for (int e = 0; e < NEXP; ++e) acc[e] = 0.0f;
#pragma unroll
    for (int it = 0; it < D_DIM / 64; ++it) {
        int d = it * 64 + lane;
        float xv = xr[d];
        const float* wr = Wr + d * NEXP;
#pragma unroll
        for (int e = 0; e < NEXP; ++e) acc[e] = fmaf(xv, wr[e], acc[e]);
    }
#pragma unroll
    for (int off = 32; off >= 1; off >>= 1) {
#pragma unroll
        for (int e = 0; e < NEXP; ++e) acc[e] += __shfl_xor(acc[e], off);
    }
    if (lane == 0) {
        int i0 = 0;
#pragma unroll
        for (int e = 1; e < NEXP; ++e) if (acc[e] > acc[i0]) i0 = e;   // ties -> lower idx
        int i1 = (i0 == 0) ? 1 : 0;
#pragma unroll
        for (int e = 0; e < NEXP; ++e) {
            if (e != i0 && acc[e] > acc[i1]) i1 = e;
        }
        float v0 = acc[i0], v1 = acc[i1];
        float ee = expf(v1 - v0);          // <= 1
        float inv = 1.0f / (1.0f + ee);
        float w0 = inv, w1 = ee * inv;
        int t = wid;
        gate_w[2 * t]     = w0;
        gate_w[2 * t + 1] = w1;
        int p0 = atomicAdd(&counts[i0], 1);
        lists[(size_t)i0 * ntok + p0] = 2 * t;
        int p1 = atomicAdd(&counts[i1], 1);
        lists[(size_t)i1 * ntok + p1] = 2 * t + 1;
    }
}

// ---------------- fused 2-layer expert MLP over gathered token tiles ---------
__global__ __launch_bounds__(TPB) void moe_kernel(
        const float* __restrict__ x,
        const float* __restrict__ W1, const float* __restrict__ b1,
        const float* __restrict__ W2, const float* __restrict__ b2,
        const float* __restrict__ gate_w,
        const int* __restrict__ lists, const int* __restrict__ counts,
        float* __restrict__ out, int ntok, int tiles) {

    __shared__ __align__(16) float ldsA[BT][KC + 4];   // X chunk, later hdn chunk
    __shared__ __align__(16) float ldsB[KC][HC + 4];   // W1 chunk, later W2 tile
    __shared__ int   toks[BT];
    __shared__ float tw[BT];

    int e    = blockIdx.x / tiles;
    int tile = blockIdx.x % tiles;
    int cnt  = counts[e];
    if (tile * BT >= cnt) return;

    int tid = threadIdx.x;
    // staging mapping: 512 threads -> 64 rows x 64 cols (8 floats each)
    int srow = tid >> 3;
    int scol = (tid & 7) * 8;
    // compute mapping: 2 tokens x 4 cols per thread
    int tg2 = tid >> 4;        // 0..31 -> tokens tg2 and tg2+32
    int sg4 = tid & 15;        // col group: 4 floats at sg4*4

    if (tid < BT) {
        int idx = tile * BT + tid;
        int entry = (idx < cnt) ? lists[(size_t)e * ntok + idx] : -1;
        toks[tid] = (entry >= 0) ? (entry >> 1) : 0;
        tw[tid]   = (entry >= 0) ? gate_w[entry] : 0.0f;
    }
    __syncthreads();

    float yacc[2][32];
#pragma unroll
    for (int p = 0; p < 2; ++p)
#pragma unroll
        for (int i = 0; i < 32; ++i) yacc[p][i] = 0.0f;

    const float* W1e = W1 + (size_t)e * D_DIM * H_DIM;
    const float* W2e = W2 + (size_t)e * H_DIM * D_DIM;
    const float* b1e = b1 + (size_t)e * H_DIM;
    int t0 = tg2, t1 = tg2 + 32;

    for (int hc = 0; hc < H_DIM / HC; ++hc) {
        float pre[2][4];
#pragma unroll
        for (int p = 0; p < 2; ++p)
#pragma unroll
            for (int j = 0; j < 4; ++j) pre[p][j] = 0.0f;

        for (int kc = 0; kc < D_DIM / KC; ++kc) {
            __syncthreads();   // protect prior reads of ldsA/ldsB
            {
                const float* src = x + (size_t)toks[srow] * D_DIM + kc * KC + scol;
                float4 a0 = *(const float4*)(src);
                float4 a1 = *(const float4*)(src + 4);
                *(float4*)&ldsA[srow][scol]     = a0;
                *(float4*)&ldsA[srow][scol + 4] = a1;
                const float* ws1 = W1e + (size_t)(kc * KC + srow) * H_DIM + hc * HC + scol;
                float4 c0 = *(const float4*)(ws1);
                float4 c1 = *(const float4*)(ws1 + 4);
                *(float4*)&ldsB[srow][scol]     = c0;
                *(float4*)&ldsB[srow][scol + 4] = c1;
            }
            __syncthreads();
#pragma unroll
            for (int k = 0; k < KC; ++k) {
                float a0 = ldsA[t0][k];
                float a1 = ldsA[t1][k];
                const float4 b4 = *(const float4*)&ldsB[k][sg4 * 4];
                pre[0][0] = fmaf(a0, b4.x, pre[0][0]);
                pre[0][1] = fmaf(a0, b4.y, pre[0][1]);
                pre[0][2] = fmaf(a0, b4.z, pre[0][2]);
                pre[0][3] = fmaf(a0, b4.w, pre[0][3]);
                pre[1][0] = fmaf(a1, b4.x, pre[1][0]);
                pre[1][1] = fmaf(a1, b4.y, pre[1][1]);
                pre[1][2] = fmaf(a1, b4.z, pre[1][2]);
                pre[1][3] = fmaf(a1, b4.w, pre[1][3]);
            }
        }
        // bias + gelu -> hdn chunk into ldsA
        __syncthreads();
        {
            const float* b1p = b1e + hc * HC + sg4 * 4;
            float4 h0, h1;
            h0.x = gelu_exact(pre[0][0] + b1p[0]);
            h0.y = gelu_exact(pre[0][1] + b1p[1]);
            h0.z = gelu_exact(pre[0][2] + b1p[2]);
            h0.w = gelu_exact(pre[0][3] + b1p[3]);
            h1.x = gelu_exact(pre[1][0] + b1p[0]);
            h1.y = gelu_exact(pre[1][1] + b1p[1]);
            h1.z = gelu_exact(pre[1][2] + b1p[2]);
            h1.w = gelu_exact(pre[1][3] + b1p[3]);
            *(float4*)&ldsA[t0][sg4 * 4] = h0;
            *(float4*)&ldsA[t1][sg4 * 4] = h1;
        }
        // layer 2: 8 d-tiles of 64
        for (int dt = 0; dt < 8; ++dt) {
            __syncthreads();   // protect hdn writes (dt==0) / prior W2 tile reads
            {
                const float* ws2 = W2e + (size_t)(hc * HC + srow) * D_DIM + dt * 64 + scol;
                float4 c0 = *(const float4*)(ws2);
                float4 c1 = *(const float4*)(ws2 + 4);
                *(float4*)&ldsB[srow][scol]     = c0;
                *(float4*)&ldsB[srow][scol + 4] = c1;
            }
            __syncthreads();
#pragma unroll
            for (int hh = 0; hh < HC; ++hh) {
                float a0 = ldsA[t0][hh];
                float a1 = ldsA[t1][hh];
                const float4 b4 = *(const float4*)&ldsB[hh][sg4 * 4];
                yacc[0][dt * 4 + 0] = fmaf(a0, b4.x, yacc[0][dt * 4 + 0]);
                yacc[0][dt * 4 + 1] = fmaf(a0, b4.y, yacc[0][dt * 4 + 1]);
                yacc[0][dt * 4 + 2] = fmaf(a0, b4.z, yacc[0][dt * 4 + 2]);
                yacc[0][dt * 4 + 3] = fmaf(a0, b4.w, yacc[0][dt * 4 + 3]);
                yacc[1][dt * 4 + 0] = fmaf(a1, b4.x, yacc[1][dt * 4 + 0]);
                yacc[1][dt * 4 + 1] = fmaf(a1, b4.y, yacc[1][dt * 4 + 1]);
                yacc[1][dt * 4 + 2] = fmaf(a1, b4.z, yacc[1][dt * 4 + 2]);
                yacc[1][dt * 4 + 3] = fmaf(a1, b4.w, yacc[1][dt * 4 + 3]);
            }
        }
    }

    // epilogue: out[tok] += w * (y + b2)
    const float* b2e = b2 + (size_t)e * D_DIM;
#pragma unroll
    for (int p = 0; p < 2; ++p) {
        int slot = (p == 0) ? t0 : t1;
        if (tile * BT + slot < cnt) {
            float w = tw[slot];
            float* op = out + (size_t)toks[slot] * D_DIM;
#pragma unroll
            for (int dt = 0; dt < 8; ++dt) {
#pragma unroll
                for (int j = 0; j < 4; ++j) {
                    int d = dt * 64 + sg4 * 4 + j;
                    atomicAdd(&op[d], w * (yacc[p][dt * 4 + j] + b2e[d]));
                }
            }
        }
    }
}

extern "C" void kernel_launch(void* const* d_in, const int* in_sizes, int n_in,
                              void* d_out, int out_size, void* d_ws, size_t ws_size,
                              hipStream_t stream) {
    const float* x  = (const float*)d_in[0];
    const float* Wr = (const float*)d_in[1];
    const float* W1 = (const float*)d_in[2];
    const float* b1 = (const float*)d_in[3];
    const float* W2 = (const float*)d_in[4];
    const float* b2 = (const float*)d_in[5];
    float* out = (float*)d_out;
    int ntok = in_sizes[0] / D_DIM;            // 16384

    int*   counts = (int*)d_ws;                                      // 8 ints (256 B pad)
    float* gate_w = (float*)((char*)d_ws + 256);                     // 2*ntok floats
    int*   lists  = (int*)((char*)d_ws + 256 + (size_t)2 * ntok * 4); // NEXP*ntok ints

    hipMemsetAsync(d_ws, 0, 256, stream);
    hipMemsetAsync(d_out, 0, (size_t)out_size * sizeof(float), stream);

    router_kernel<<<(ntok + 3) / 4, 256, 0, stream>>>(x, Wr, gate_w, lists, counts, ntok);

    int tiles = (ntok + BT - 1) / BT;          // 256
    moe_kernel<<<NEXP * tiles, TPB, 0, stream>>>(x, W1, b1, W2, b2,
                                                 gate_w, lists, counts, out, ntok, tiles);
}

// Round 2
// 1004.988 us; speedup vs baseline: 4.2393x; 4.2393x over previous
//
#include <hip/hip_runtime.h>
#include <math.h>

#define D_DIM 512
#define H_DIM 2048
#define NEXP  8

typedef __bf16 bf16x8 __attribute__((ext_vector_type(8)));
typedef float  f32x4  __attribute__((ext_vector_type(4)));

__device__ __forceinline__ unsigned short f2b(float f) {
    unsigned int u = __float_as_uint(f);
    unsigned int r = (u + 0x7FFFu + ((u >> 16) & 1u)) >> 16;
    return (unsigned short)r;
}

// exact-ish gelu: erf via Abramowitz-Stegun 7.1.26 (|err| < 1.5e-7)
__device__ __forceinline__ float gelu_f(float v) {
    float z = fabsf(v) * 0.70710678118654752440f;
    float t = __builtin_amdgcn_rcpf(fmaf(0.3275911f, z, 1.0f));
    float poly = t * (0.254829592f +
                 t * (-0.284496736f +
                 t * (1.421413741f +
                 t * (-1.453152027f +
                 t * 1.061405429f))));
    float er = 1.0f - poly * __expf(-z * z);
    er = (v < 0.0f) ? -er : er;
    return 0.5f * v * (1.0f + er);
}

__device__ __forceinline__ void async_cp16(const void* g, void* l) {
    __builtin_amdgcn_global_load_lds(
        (const __attribute__((address_space(1))) unsigned int*)g,
        (__attribute__((address_space(3))) unsigned int*)l, 16, 0, 0);
}

// ---------------- converts -------------------------------------------------
__global__ void convert_x_kernel(const float* __restrict__ in,
                                 unsigned short* __restrict__ out, int n8) {
    int i = blockIdx.x * blockDim.x + threadIdx.x;
    if (i >= n8) return;
    const float4* p = (const float4*)(in + (size_t)i * 8);
    float4 a = p[0], b = p[1];
    unsigned short r[8] = {f2b(a.x), f2b(a.y), f2b(a.z), f2b(a.w),
                           f2b(b.x), f2b(b.y), f2b(b.z), f2b(b.w)};
    *(uint4*)(out + (size_t)i * 8) = *(const uint4*)r;
}

// in [e][R][C] f32 -> out [e][C][R] bf16
__global__ void transpose_conv_kernel(const float* __restrict__ in,
                                      unsigned short* __restrict__ out,
                                      int R, int C) {
    __shared__ unsigned short tile[64][72];
    int e = blockIdx.z;
    const float* ine = in + (size_t)e * R * C;
    unsigned short* oute = out + (size_t)e * C * R;
    int r0 = blockIdx.y * 64, c0 = blockIdx.x * 64;
    int tid = threadIdx.x;
#pragma unroll
    for (int rd = 0; rd < 4; ++rd) {
        int r = (tid >> 4) + rd * 16;
        int c = (tid & 15) * 4;
        float4 v = *(const float4*)&ine[(size_t)(r0 + r) * C + c0 + c];
        tile[c + 0][r] = f2b(v.x);
        tile[c + 1][r] = f2b(v.y);
        tile[c + 2][r] = f2b(v.z);
        tile[c + 3][r] = f2b(v.w);
    }
    __syncthreads();
    int cc = tid >> 2, rc = (tid & 3) * 16;
    unsigned short* op = oute + (size_t)(c0 + cc) * R + r0 + rc;
    *(uint4*)(op)     = *(const uint4*)&tile[cc][rc];
    *(uint4*)(op + 8) = *(const uint4*)&tile[cc][rc + 8];
}

// ---------------- router ---------------------------------------------------
__global__ void router_kernel(const float* __restrict__ x,
                              const float* __restrict__ Wr,
                              float* __restrict__ gate_w,
                              int* __restrict__ lists,
                              int* __restrict__ counts,
                              int* __restrict__ route,
                              int ntok) {
    int wid  = (blockIdx.x * blockDim.x + threadIdx.x) >> 6;
    int lane = threadIdx.x & 63;
    if (wid >= ntok) return;
    const float* xr = x + (size_t)wid * D_DIM;
    float acc[NEXP];
#pragma unroll
    for (int e = 0; e < NEXP; ++e) acc[e] = 0.0f;
#pragma unroll
    for (int it = 0; it < D_DIM / 64; ++it) {
        int d = it * 64 + lane;
        float xv = xr[d];
        const float* wr = Wr + d * NEXP;
#pragma unroll
        for (int e = 0; e < NEXP; ++e) acc[e] = fmaf(xv, wr[e], acc[e]);
    }
#pragma unroll
    for (int off = 32; off >= 1; off >>= 1) {
#pragma unroll
        for (int e = 0; e < NEXP; ++e) acc[e] += __shfl_xor(acc[e], off);
    }
    if (lane == 0) {
        int i0 = 0;
#pragma unroll
        for (int e = 1; e < NEXP; ++e) if (acc[e] > acc[i0]) i0 = e;
        int i1 = (i0 == 0) ? 1 : 0;
#pragma unroll
        for (int e = 0; e < NEXP; ++e) {
            if (e != i0 && acc[e] > acc[i1]) i1 = e;
        }
        float v0 = acc[i0], v1 = acc[i1];
        float ee = expf(v1 - v0);
        float inv = 1.0f / (1.0f + ee);
        int t = wid;
        gate_w[2 * t]     = inv;
        gate_w[2 * t + 1] = ee * inv;
        route[t] = i0 | (i1 << 8);
        int p0 = atomicAdd(&counts[i0], 1);
        lists[(size_t)i0 * ntok + p0] = 2 * t;
        int p1 = atomicAdd(&counts[i1], 1);
        lists[(size_t)i1 * ntok + p1] = 2 * t + 1;
    }
}

__global__ void prefix_kernel(int* cb) {
    if (threadIdx.x == 0 && blockIdx.x == 0) {
        int s = 0;
#pragma unroll
        for (int e = 0; e < NEXP; ++e) { cb[8 + e] = s; s += cb[e]; }
    }
}

// out[tok] = w0*b2[e0] + w1*b2[e1]   (full coverage -> no memset needed)
__global__ void bias_gate_kernel(const int* __restrict__ route,
                                 const float* __restrict__ gate_w,
                                 const float* __restrict__ b2,
                                 float* __restrict__ out, int ntok) {
    int t = blockIdx.x * 4 + (threadIdx.x >> 6);
    int lane = threadIdx.x & 63;
    if (t >= ntok) return;
    int rt = route[t];
    int e0 = rt & 255, e1 = (rt >> 8) & 255;
    float w0 = gate_w[2 * t], w1 = gate_w[2 * t + 1];
    const float4* p0 = (const float4*)(b2 + (size_t)e0 * D_DIM);
    const float4* p1 = (const float4*)(b2 + (size_t)e1 * D_DIM);
    float4* po = (float4*)(out + (size_t)t * D_DIM);
#pragma unroll
    for (int j = 0; j < 2; ++j) {
        float4 a = p0[lane * 2 + j], b = p1[lane * 2 + j];
        float4 r;
        r.x = w0 * a.x + w1 * b.x;
        r.y = w0 * a.y + w1 * b.y;
        r.z = w0 * a.z + w1 * b.z;
        r.w = w0 * a.w + w1 * b.w;
        po[lane * 2 + j] = r;
    }
}

// ---------------- pass 1: hdn = gate * gelu(Xg @ W1 + b1) ------------------
// block tile 128(M) x 256(N), BK=64; 4 waves, wave tile 128x64 (8m x 4n frags)
#define BM 128
#define BN 256
#define BK 64

__global__ __launch_bounds__(256, 2) void gemm1_kernel(
        const unsigned short* __restrict__ xb,    // [ntok][512] bf16
        const unsigned short* __restrict__ W1T,   // [E][2048][512] bf16
        const float* __restrict__ b1,             // [E][2048]
        const float* __restrict__ gate_w,
        const int* __restrict__ lists,
        const int* __restrict__ cb,               // counts[0..7] bases[8..15]
        unsigned short* __restrict__ hdn,         // [2*ntok][2048] bf16
        int ntok) {
    int bid = blockIdx.x;
    int e = bid & 7;
    int rest = bid >> 3;
    int ntile = rest & 7;          // 2048/256
    int mt = rest >> 3;
    int cnt = cb[e];
    if (mt * BM >= cnt) return;
    int base = cb[8 + e];

    __shared__ unsigned short Bs[2][BN * BK];   // [n][k] swizzled, 32 KB each
    __shared__ int   toksS[BM];
    __shared__ float twS[BM];

    int tid = threadIdx.x;
    int l = tid & 63, w = tid >> 6;

    if (tid < BM) {
        int idx = mt * BM + tid;
        int entry = (idx < cnt) ? lists[(size_t)e * ntok + idx] : -1;
        toksS[tid] = (entry >= 0) ? (entry >> 1) : 0;
        twS[tid]   = (entry >= 0) ? gate_w[entry] : 0.0f;
    }
    __syncthreads();

    const unsigned short* W1e = W1T + (size_t)e * H_DIM * D_DIM;
    unsigned int uoff = (unsigned int)(((l & 7) ^ (l >> 3)) * 8);
    unsigned int srcB[8];
    int nrow = ntile * BN + w * 64 + (l >> 3);
#pragma unroll
    for (int c = 0; c < 8; ++c)
        srcB[c] = (unsigned int)((nrow + 8 * c) * D_DIM) + uoff;
    unsigned int abase[8];
#pragma unroll
    for (int mf = 0; mf < 8; ++mf)
        abase[mf] = (unsigned int)toksS[mf * 16 + (l & 15)] * D_DIM
                  + (unsigned int)((l >> 4) * 8);

    f32x4 acc[8][4];
#pragma unroll
    for (int i = 0; i < 8; ++i)
#pragma unroll
        for (int j = 0; j < 4; ++j) acc[i][j] = (f32x4){0.f, 0.f, 0.f, 0.f};

    char* dstbase = (char*)(&Bs[0][0]) + (size_t)w * 8192;
    const char* srcbase = (const char*)W1e;

    // prologue: stage buf 0 (kc = 0)
#pragma unroll
    for (int c = 0; c < 8; ++c)
        async_cp16(srcbase + (size_t)srcB[c] * 2, dstbase + c * 1024);
    __syncthreads();

    const int NT = D_DIM / BK;   // 8
    for (int kc = 0; kc < NT; ++kc) {
        int cur = kc & 1;
        if (kc + 1 < NT) {
            char* db = dstbase + (cur ^ 1) * (BN * BK * 2);
            size_t ko = (size_t)(kc + 1) * BK * 2;
#pragma unroll
            for (int c = 0; c < 8; ++c)
                async_cp16(srcbase + (size_t)srcB[c] * 2 + ko, db + c * 1024);
        }
        const unsigned short* Bc = &Bs[cur][0];
#pragma unroll
        for (int ks = 0; ks < 2; ++ks) {
            bf16x8 av[8];
#pragma unroll
            for (int mf = 0; mf < 8; ++mf)
                av[mf] = *(const bf16x8*)(xb + abase[mf] + kc * 64 + ks * 32);
            bf16x8 bv[4];
            unsigned int u = (unsigned int)((ks * 4 + (l >> 4)) ^ (l & 7));
#pragma unroll
            for (int nf = 0; nf < 4; ++nf) {
                int nloc = w * 64 + nf * 16 + (l & 15);
                bv[nf] = *(const bf16x8*)(Bc + nloc * 64 + u * 8);
            }
#pragma unroll
            for (int mf = 0; mf < 8; ++mf)
#pragma unroll
                for (int nf = 0; nf < 4; ++nf)
                    acc[mf][nf] = __builtin_amdgcn_mfma_f32_16x16x32_bf16(
                        av[mf], bv[nf], acc[mf][nf], 0, 0, 0);
        }
        __syncthreads();
    }

    // epilogue: bias + gelu + gate, store bf16
    float twr[32];
#pragma unroll
    for (int mf = 0; mf < 8; ++mf)
#pragma unroll
        for (int r = 0; r < 4; ++r)
            twr[mf * 4 + r] = twS[mf * 16 + (l >> 4) * 4 + r];
    const float* b1e = b1 + (size_t)e * H_DIM + ntile * BN;
#pragma unroll
    for (int nf = 0; nf < 4; ++nf) {
        int col = w * 64 + nf * 16 + (l & 15);
        float b1v = b1e[col];
#pragma unroll
        for (int mf = 0; mf < 8; ++mf) {
#pragma unroll
            for (int r = 0; r < 4; ++r) {
                int row = mf * 16 + (l >> 4) * 4 + r;
                int gr = mt * BM + row;
                if (gr < cnt) {
                    float hv = twr[mf * 4 + r] * gelu_f(acc[mf][nf][r] + b1v);
                    hdn[(size_t)(base + gr) * H_DIM + ntile * BN + col] = f2b(hv);
                }
            }
        }
    }
}

// ---------------- pass 2: out[tok] += hdn @ W2T ----------------------------
__global__ __launch_bounds__(256, 2) void gemm2_kernel(
        const unsigned short* __restrict__ hdn,   // [2*ntok][2048] bf16
        const unsigned short* __restrict__ W2T,   // [E][512][2048] bf16
        const int* __restrict__ lists,
        const int* __restrict__ cb,
        float* __restrict__ out,
        int ntok) {
    int bid = blockIdx.x;
    int e = bid & 7;
    int rest = bid >> 3;
    int ntile = rest & 1;          // 512/256
    int mt = rest >> 1;
    int cnt = cb[e];
    if (mt * BM >= cnt) return;
    int base = cb[8 + e];

    __shared__ unsigned short Bs[2][BN * BK];
    __shared__ int toksS[BM];

    int tid = threadIdx.x;
    int l = tid & 63, w = tid >> 6;

    if (tid < BM) {
        int idx = mt * BM + tid;
        int entry = (idx < cnt) ? lists[(size_t)e * ntok + idx] : -1;
        toksS[tid] = (entry >= 0) ? (entry >> 1) : 0;
    }
    __syncthreads();

    const unsigned short* W2e = W2T + (size_t)e * D_DIM * H_DIM;
    unsigned int uoff = (unsigned int)(((l & 7) ^ (l >> 3)) * 8);
    unsigned int srcB[8];
    int nrow = ntile * BN + w * 64 + (l >> 3);
#pragma unroll
    for (int c = 0; c < 8; ++c)
        srcB[c] = (unsigned int)((nrow + 8 * c) * H_DIM) + uoff;
    int hlimit = 2 * ntok - 1;
    unsigned int abase[8];
#pragma unroll
    for (int mf = 0; mf < 8; ++mf) {
        int row = base + mt * BM + mf * 16 + (l & 15);
        row = (row > hlimit) ? hlimit : row;
        abase[mf] = (unsigned int)row * H_DIM + (unsigned int)((l >> 4) * 8);
    }

    f32x4 acc[8][4];
#pragma unroll
    for (int i = 0; i < 8; ++i)
#pragma unroll
        for (int j = 0; j < 4; ++j) acc[i][j] = (f32x4){0.f, 0.f, 0.f, 0.f};

    char* dstbase = (char*)(&Bs[0][0]) + (size_t)w * 8192;
    const char* srcbase = (const char*)W2e;

#pragma unroll
    for (int c = 0; c < 8; ++c)
        async_cp16(srcbase + (size_t)srcB[c] * 2, dstbase + c * 1024);
    __syncthreads();

    const int NT = H_DIM / BK;   // 32
    for (int kc = 0; kc < NT; ++kc) {
        int cur = kc & 1;
        if (kc + 1 < NT) {
            char* db = dstbase + (cur ^ 1) * (BN * BK * 2);
            size_t ko = (size_t)(kc + 1) * BK * 2;
#pragma unroll
            for (int c = 0; c < 8; ++c)
                async_cp16(srcbase + (size_t)srcB[c] * 2 + ko, db + c * 1024);
        }
        const unsigned short* Bc = &Bs[cur][0];
#pragma unroll
        for (int ks = 0; ks < 2; ++ks) {
            bf16x8 av[8];
#pragma unroll
            for (int mf = 0; mf < 8; ++mf)
                av[mf] = *(const bf16x8*)(hdn + abase[mf] + kc * 64 + ks * 32);
            bf16x8 bv[4];
            unsigned int u = (unsigned int)((ks * 4 + (l >> 4)) ^ (l & 7));
#pragma unroll
            for (int nf = 0; nf < 4; ++nf) {
                int nloc = w * 64 + nf * 16 + (l & 15);
                bv[nf] = *(const bf16x8*)(Bc + nloc * 64 + u * 8);
            }
#pragma unroll
            for (int mf = 0; mf < 8; ++mf)
#pragma unroll
                for (int nf = 0; nf < 4; ++nf)
                    acc[mf][nf] = __builtin_amdgcn_mfma_f32_16x16x32_bf16(
                        av[mf], bv[nf], acc[mf][nf], 0, 0, 0);
        }
        __syncthreads();
    }

    // epilogue: scatter atomicAdd (b2+gate handled by bias_gate_kernel)
    int tokr[32];
#pragma unroll
    for (int mf = 0; mf < 8; ++mf)
#pragma unroll
        for (int r = 0; r < 4; ++r)
            tokr[mf * 4 + r] = toksS[mf * 16 + (l >> 4) * 4 + r];
#pragma unroll
    for (int mf = 0; mf < 8; ++mf) {
#pragma unroll
        for (int r = 0; r < 4; ++r) {
            int row = mf * 16 + (l >> 4) * 4 + r;
            int gr = mt * BM + row;
            if (gr < cnt) {
                float* op = out + (size_t)tokr[mf * 4 + r] * D_DIM;
#pragma unroll
                for (int nf = 0; nf < 4; ++nf) {
                    int col = ntile * BN + w * 64 + nf * 16 + (l & 15);
                    atomicAdd(op + col, acc[mf][nf][r]);
                }
            }
        }
    }
}

// ================= round-1 fallback (small workspace) ======================
#define FBT 64
#define FKC 64
#define FHC 64
#define FTPB 512

__global__ __launch_bounds__(FTPB) void moe_fused_fallback(
        const float* __restrict__ x,
        const float* __restrict__ W1, const float* __restrict__ b1,
        const float* __restrict__ W2, const float* __restrict__ b2,
        const float* __restrict__ gate_w,
        const int* __restrict__ lists, const int* __restrict__ counts,
        float* __restrict__ out, int ntok, int tiles) {
    __shared__ __align__(16) float ldsA[FBT][FKC + 4];
    __shared__ __align__(16) float ldsB[FKC][FHC + 4];
    __shared__ int   toks[FBT];
    __shared__ float tw[FBT];
    int e = blockIdx.x / tiles;
    int tile = blockIdx.x % tiles;
    int cnt = counts[e];
    if (tile * FBT >= cnt) return;
    int tid = threadIdx.x;
    int srow = tid >> 3, scol = (tid & 7) * 8;
    int tg2 = tid >> 4, sg4 = tid & 15;
    if (tid < FBT) {
        int idx = tile * FBT + tid;
        int entry = (idx < cnt) ? lists[(size_t)e * ntok + idx] : -1;
        toks[tid] = (entry >= 0) ? (entry >> 1) : 0;
        tw[tid]   = (entry >= 0) ? gate_w[entry] : 0.0f;
    }
    __syncthreads();
    float yacc[2][32];
#pragma unroll
    for (int p = 0; p < 2; ++p)
#pragma unroll
        for (int i = 0; i < 32; ++i) yacc[p][i] = 0.0f;
    const float* W1e = W1 + (size_t)e * D_DIM * H_DIM;
    const float* W2e = W2 + (size_t)e * H_DIM * D_DIM;
    const float* b1e = b1 + (size_t)e * H_DIM;
    int t0 = tg2, t1 = tg2 + 32;
    for (int hc = 0; hc < H_DIM / FHC; ++hc) {
        float pre[2][4];
#pragma unroll
        for (int p = 0; p < 2; ++p)
#pragma unroll
            for (int j = 0; j < 4; ++j) pre[p][j] = 0.0f;
        for (int kc = 0; kc < D_DIM / FKC; ++kc) {
            __syncthreads();
            {
                const float* src = x + (size_t)toks[srow] * D_DIM + kc * FKC + scol;
                *(float4*)&ldsA[srow][scol]     = *(const float4*)(src);
                *(float4*)&ldsA[srow][scol + 4] = *(const float4*)(src + 4);
                const float* ws1 = W1e + (size_t)(kc * FKC + srow) * H_DIM + hc * FHC + scol;
                *(float4*)&ldsB[srow][scol]     = *(const float4*)(ws1);
                *(float4*)&ldsB[srow][scol + 4] = *(const float4*)(ws1 + 4);
            }
            __syncthreads();
#pragma unroll
            for (int k = 0; k < FKC; ++k) {
                float a0 = ldsA[t0][k], a1 = ldsA[t1][k];
                const float4 b4 = *(const float4*)&ldsB[k][sg4 * 4];
                pre[0][0] = fmaf(a0, b4.x, pre[0][0]);
                pre[0][1] = fmaf(a0, b4.y, pre[0][1]);
                pre[0][2] = fmaf(a0, b4.z, pre[0][2]);
                pre[0][3] = fmaf(a0, b4.w, pre[0][3]);
                pre[1][0] = fmaf(a1, b4.x, pre[1][0]);
                pre[1][1] = fmaf(a1, b4.y, pre[1][1]);
                pre[1][2] = fmaf(a1, b4.z, pre[1][2]);
                pre[1][3] = fmaf(a1, b4.w, pre[1][3]);
            }
        }
        __syncthreads();
        {
            const float* b1p = b1e + hc * FHC + sg4 * 4;
            float4 h0, h1;
            h0.x = gelu_f(pre[0][0] + b1p[0]); h0.y = gelu_f(pre[0][1] + b1p[1]);
            h0.z = gelu_f(pre[0][2] + b1p[2]); h0.w = gelu_f(pre[0][3] + b1p[3]);
            h1.x = gelu_f(pre[1][0] + b1p[0]); h1.y = gelu_f(pre[1][1] + b1p[1]);
            h1.z = gelu_f(pre[1][2] + b1p[2]); h1.w = gelu_f(pre[1][3] + b1p[3]);
            *(float4*)&ldsA[t0][sg4 * 4] = h0;
            *(float4*)&ldsA[t1][sg4 * 4] = h1;
        }
        for (int dt = 0; dt < 8; ++dt) {
            __syncthreads();
            {
                const float* ws2 = W2e + (size_t)(hc * FHC + srow) * D_DIM + dt * 64 + scol;
                *(float4*)&ldsB[srow][scol]     = *(const float4*)(ws2);
                *(float4*)&ldsB[srow][scol + 4] = *(const float4*)(ws2 + 4);
            }
            __syncthreads();
#pragma unroll
            for (int hh = 0; hh < FHC; ++hh) {
                float a0 = ldsA[t0][hh], a1 = ldsA[t1][hh];
                const float4 b4 = *(const float4*)&ldsB[hh][sg4 * 4];
                yacc[0][dt * 4 + 0] = fmaf(a0, b4.x, yacc[0][dt * 4 + 0]);
                yacc[0][dt * 4 + 1] = fmaf(a0, b4.y, yacc[0][dt * 4 + 1]);
                yacc[0][dt * 4 + 2] = fmaf(a0, b4.z, yacc[0][dt * 4 + 2]);
                yacc[0][dt * 4 + 3] = fmaf(a0, b4.w, yacc[0][dt * 4 + 3]);
                yacc[1][dt * 4 + 0] = fmaf(a1, b4.x, yacc[1][dt * 4 + 0]);
                yacc[1][dt * 4 + 1] = fmaf(a1, b4.y, yacc[1][dt * 4 + 1]);
                yacc[1][dt * 4 + 2] = fmaf(a1, b4.z, yacc[1][dt * 4 + 2]);
                yacc[1][dt * 4 + 3] = fmaf(a1, b4.w, yacc[1][dt * 4 + 3]);
            }
        }
    }
    const float* b2e = b2 + (size_t)e * D_DIM;
#pragma unroll
    for (int p = 0; p < 2; ++p) {
        int slot = (p == 0) ? t0 : t1;
        if (tile * FBT + slot < cnt) {
            float wv = tw[slot];
            float* op = out + (size_t)toks[slot] * D_DIM;
#pragma unroll
            for (int dt = 0; dt < 8; ++dt)
#pragma unroll
                for (int j = 0; j < 4; ++j) {
                    int d = dt * 64 + sg4 * 4 + j;
                    atomicAdd(&op[d], wv * (yacc[p][dt * 4 + j] + b2e[d]));
                }
        }
    }
}

// ===========================================================================
extern "C" void kernel_launch(void* const* d_in, const int* in_sizes, int n_in,
                              void* d_out, int out_size, void* d_ws, size_t ws_size,
                              hipStream_t stream) {
    const float* x  = (const float*)d_in[0];
    const float* Wr = (const float*)d_in[1];
    const float* W1 = (const float*)d_in[2];
    const float* b1 = (const float*)d_in[3];
    const float* W2 = (const float*)d_in[4];
    const float* b2 = (const float*)d_in[5];
    float* out = (float*)d_out;
    int ntok = in_sizes[0] / D_DIM;   // 16384

    size_t off_route = 256;
    size_t off_gate  = off_route + (size_t)ntok * 4;
    size_t off_lists = off_gate + (size_t)2 * ntok * 4;
    size_t off_xb    = off_lists + (size_t)NEXP * ntok * 4;
    size_t off_w1t   = off_xb + (size_t)ntok * D_DIM * 2;
    size_t off_w2t   = off_w1t + (size_t)NEXP * D_DIM * H_DIM * 2;
    size_t off_hdn   = off_w2t + (size_t)NEXP * D_DIM * H_DIM * 2;
    size_t need      = off_hdn + (size_t)2 * ntok * H_DIM * 2;

    int*   cb     = (int*)d_ws;
    int*   route  = (int*)((char*)d_ws + off_route);
    float* gate_w = (float*)((char*)d_ws + off_gate);
    int*   lists  = (int*)((char*)d_ws + off_lists);

    hipMemsetAsync(d_ws, 0, 256, stream);

    if (ws_size >= need) {
        unsigned short* xb  = (unsigned short*)((char*)d_ws + off_xb);
        unsigned short* W1T = (unsigned short*)((char*)d_ws + off_w1t);
        unsigned short* W2T = (unsigned short*)((char*)d_ws + off_w2t);
        unsigned short* hdn = (unsigned short*)((char*)d_ws + off_hdn);

        int n8 = ntok * D_DIM / 8;
        convert_x_kernel<<<(n8 + 255) / 256, 256, 0, stream>>>(x, xb, n8);
        transpose_conv_kernel<<<dim3(H_DIM / 64, D_DIM / 64, NEXP), 256, 0, stream>>>(
            W1, W1T, D_DIM, H_DIM);
        transpose_conv_kernel<<<dim3(D_DIM / 64, H_DIM / 64, NEXP), 256, 0, stream>>>(
            W2, W2T, H_DIM, D_DIM);
        router_kernel<<<(ntok + 3) / 4, 256, 0, stream>>>(
            x, Wr, gate_w, lists, cb, route, ntok);
        prefix_kernel<<<1, 64, 0, stream>>>(cb);
        bias_gate_kernel<<<(ntok + 3) / 4, 256, 0, stream>>>(
            route, gate_w, b2, out, ntok);
        int mtiles = ntok / BM;   // 128
        gemm1_kernel<<<NEXP * (H_DIM / BN) * mtiles, 256, 0, stream>>>(
            xb, W1T, b1, gate_w, lists, cb, hdn, ntok);
        gemm2_kernel<<<NEXP * (D_DIM / BN) * mtiles, 256, 0, stream>>>(
            hdn, W2T, lists, cb, out, ntok);
    } else {
        hipMemsetAsync(d_out, 0, (size_t)out_size * sizeof(float), stream);
        router_kernel<<<(ntok + 3) / 4, 256, 0, stream>>>(
            x, Wr, gate_w, lists, cb, route, ntok);
        int tiles = (ntok + FBT - 1) / FBT;
        moe_fused_fallback<<<NEXP * tiles, FTPB, 0, stream>>>(
            x, W1, b1, W2, b2, gate_w, lists, cb, out, ntok, tiles);
    }
}

// Round 3
// 661.671 us; speedup vs baseline: 6.4389x; 1.5189x over previous
//
#include <hip/hip_runtime.h>
#include <math.h>

#define D_DIM 512
#define H_DIM 2048
#define NEXP  8

typedef __bf16 bf16x8 __attribute__((ext_vector_type(8)));
typedef float  f32x4  __attribute__((ext_vector_type(4)));

__device__ __forceinline__ unsigned short f2b(float f) {
    unsigned int u = __float_as_uint(f);
    unsigned int r = (u + 0x7FFFu + ((u >> 16) & 1u)) >> 16;
    return (unsigned short)r;
}

// exact-ish gelu: erf via Abramowitz-Stegun 7.1.26 (|err| < 1.5e-7)
__device__ __forceinline__ float gelu_f(float v) {
    float z = fabsf(v) * 0.70710678118654752440f;
    float t = __builtin_amdgcn_rcpf(fmaf(0.3275911f, z, 1.0f));
    float poly = t * (0.254829592f +
                 t * (-0.284496736f +
                 t * (1.421413741f +
                 t * (-1.453152027f +
                 t * 1.061405429f))));
    float er = 1.0f - poly * __expf(-z * z);
    er = (v < 0.0f) ? -er : er;
    return 0.5f * v * (1.0f + er);
}

__device__ __forceinline__ void async_cp16(const void* g, void* l) {
    __builtin_amdgcn_global_load_lds(
        (const __attribute__((address_space(1))) unsigned int*)g,
        (__attribute__((address_space(3))) unsigned int*)l, 16, 0, 0);
}

// ---------------- converts -------------------------------------------------
__global__ void convert_x_kernel(const float* __restrict__ in,
                                 unsigned short* __restrict__ out, int n8) {
    int i = blockIdx.x * blockDim.x + threadIdx.x;
    if (i >= n8) return;
    const float4* p = (const float4*)(in + (size_t)i * 8);
    float4 a = p[0], b = p[1];
    unsigned short r[8] = {f2b(a.x), f2b(a.y), f2b(a.z), f2b(a.w),
                           f2b(b.x), f2b(b.y), f2b(b.z), f2b(b.w)};
    *(uint4*)(out + (size_t)i * 8) = *(const uint4*)r;
}

// in [e][R][C] f32 -> out [e][C][R] bf16
__global__ void transpose_conv_kernel(const float* __restrict__ in,
                                      unsigned short* __restrict__ out,
                                      int R, int C) {
    __shared__ unsigned short tile[64][72];
    int e = blockIdx.z;
    const float* ine = in + (size_t)e * R * C;
    unsigned short* oute = out + (size_t)e * C * R;
    int r0 = blockIdx.y * 64, c0 = blockIdx.x * 64;
    int tid = threadIdx.x;
#pragma unroll
    for (int rd = 0; rd < 4; ++rd) {
        int r = (tid >> 4) + rd * 16;
        int c = (tid & 15) * 4;
        float4 v = *(const float4*)&ine[(size_t)(r0 + r) * C + c0 + c];
        tile[c + 0][r] = f2b(v.x);
        tile[c + 1][r] = f2b(v.y);
        tile[c + 2][r] = f2b(v.z);
        tile[c + 3][r] = f2b(v.w);
    }
    __syncthreads();
    int cc = tid >> 2, rc = (tid & 3) * 16;
    unsigned short* op = oute + (size_t)(c0 + cc) * R + r0 + rc;
    *(uint4*)(op)     = *(const uint4*)&tile[cc][rc];
    *(uint4*)(op + 8) = *(const uint4*)&tile[cc][rc + 8];
}

// ---------------- router: per-token top2+softmax only (NO atomics) ---------
__global__ void router_kernel(const float* __restrict__ x,
                              const float* __restrict__ Wr,
                              float* __restrict__ gate_w,
                              int* __restrict__ route,
                              int ntok) {
    int wid  = (blockIdx.x * blockDim.x + threadIdx.x) >> 6;
    int lane = threadIdx.x & 63;
    if (wid >= ntok) return;
    const float* xr = x + (size_t)wid * D_DIM;
    float acc[NEXP];
#pragma unroll
    for (int e = 0; e < NEXP; ++e) acc[e] = 0.0f;
#pragma unroll
    for (int it = 0; it < D_DIM / 64; ++it) {
        int d = it * 64 + lane;
        float xv = xr[d];
        const float* wr = Wr + d * NEXP;
#pragma unroll
        for (int e = 0; e < NEXP; ++e) acc[e] = fmaf(xv, wr[e], acc[e]);
    }
#pragma unroll
    for (int off = 32; off >= 1; off >>= 1) {
#pragma unroll
        for (int e = 0; e < NEXP; ++e) acc[e] += __shfl_xor(acc[e], off);
    }
    if (lane == 0) {
        int i0 = 0;
#pragma unroll
        for (int e = 1; e < NEXP; ++e) if (acc[e] > acc[i0]) i0 = e;
        int i1 = (i0 == 0) ? 1 : 0;
#pragma unroll
        for (int e = 0; e < NEXP; ++e) {
            if (e != i0 && acc[e] > acc[i1]) i1 = e;
        }
        float v0 = acc[i0], v1 = acc[i1];
        float ee = expf(v1 - v0);
        float inv = 1.0f / (1.0f + ee);
        int t = wid;
        gate_w[2 * t]     = inv;
        gate_w[2 * t + 1] = ee * inv;
        route[t] = i0 | (i1 << 8);
    }
}

// ---------------- deterministic per-expert stream compaction ---------------
// 8 blocks (one per expert) x 256 threads; token-ordered lists.
__global__ void lists_kernel(const int* __restrict__ route,
                             int* __restrict__ lists,
                             int* __restrict__ cb,
                             int ntok) {
    __shared__ int wave_off[4];
    int e = blockIdx.x;
    int tid = threadIdx.x;
    int lane = tid & 63, w = tid >> 6;
    int running = 0;
    for (int c0 = 0; c0 < ntok; c0 += 256) {
        int t = c0 + tid;
        int rt = (t < ntok) ? route[t] : -1;
        int e0 = rt & 255, e1 = (rt >> 8) & 255;
        bool p1 = (e1 == e) && (rt >= 0);
        bool p  = ((e0 == e) && (rt >= 0)) || p1;
        unsigned long long mask = __ballot(p);
        int mypos = __popcll(mask & ((1ull << lane) - 1ull));
        int wcnt  = __popcll(mask);
        if (lane == 0) wave_off[w] = wcnt;
        __syncthreads();
        int wbase = 0;
#pragma unroll
        for (int i = 0; i < 4; ++i) if (i < w) wbase += wave_off[i];
        int total = wave_off[0] + wave_off[1] + wave_off[2] + wave_off[3];
        if (p) lists[(size_t)e * ntok + running + wbase + mypos] = 2 * t + (p1 ? 1 : 0);
        running += total;
        __syncthreads();
    }
    if (tid == 0) cb[e] = running;
}

__global__ void prefix_kernel(int* cb) {
    if (threadIdx.x == 0 && blockIdx.x == 0) {
        int s = 0;
#pragma unroll
        for (int e = 0; e < NEXP; ++e) { cb[8 + e] = s; s += cb[e]; }
    }
}

// out[tok] = w0*b2[e0] + w1*b2[e1]   (full coverage -> no memset needed)
__global__ void bias_gate_kernel(const int* __restrict__ route,
                                 const float* __restrict__ gate_w,
                                 const float* __restrict__ b2,
                                 float* __restrict__ out, int ntok) {
    int t = blockIdx.x * 4 + (threadIdx.x >> 6);
    int lane = threadIdx.x & 63;
    if (t >= ntok) return;
    int rt = route[t];
    int e0 = rt & 255, e1 = (rt >> 8) & 255;
    float w0 = gate_w[2 * t], w1 = gate_w[2 * t + 1];
    const float4* p0 = (const float4*)(b2 + (size_t)e0 * D_DIM);
    const float4* p1 = (const float4*)(b2 + (size_t)e1 * D_DIM);
    float4* po = (float4*)(out + (size_t)t * D_DIM);
#pragma unroll
    for (int j = 0; j < 2; ++j) {
        float4 a = p0[lane * 2 + j], b = p1[lane * 2 + j];
        float4 r;
        r.x = w0 * a.x + w1 * b.x;
        r.y = w0 * a.y + w1 * b.y;
        r.z = w0 * a.z + w1 * b.z;
        r.w = w0 * a.w + w1 * b.w;
        po[lane * 2 + j] = r;
    }
}

// ---------------- pass 1: hdn = gate * gelu(Xg @ W1 + b1) ------------------
// block tile 128(M) x 256(N), BK=64; 4 waves, wave tile 128x64 (8m x 4n frags)
#define BM 128
#define BN 256
#define BK 64

__global__ __launch_bounds__(256, 2) void gemm1_kernel(
        const unsigned short* __restrict__ xb,    // [ntok][512] bf16
        const unsigned short* __restrict__ W1T,   // [E][2048][512] bf16
        const float* __restrict__ b1,             // [E][2048]
        const float* __restrict__ gate_w,
        const int* __restrict__ lists,
        const int* __restrict__ cb,               // counts[0..7] bases[8..15]
        unsigned short* __restrict__ hdn,         // [2*ntok][2048] bf16
        int ntok) {
    int bid = blockIdx.x;
    int e = bid & 7;
    int rest = bid >> 3;
    int ntile = rest & 7;          // 2048/256
    int mt = rest >> 3;
    int cnt = cb[e];
    if (mt * BM >= cnt) return;
    int base = cb[8 + e];

    __shared__ unsigned short Bs[2][BN * BK];   // [n][k] swizzled, 32 KB each
    __shared__ int   toksS[BM];
    __shared__ float twS[BM];

    int tid = threadIdx.x;
    int l = tid & 63, w = tid >> 6;

    if (tid < BM) {
        int idx = mt * BM + tid;
        int entry = (idx < cnt) ? lists[(size_t)e * ntok + idx] : -1;
        toksS[tid] = (entry >= 0) ? (entry >> 1) : 0;
        twS[tid]   = (entry >= 0) ? gate_w[entry] : 0.0f;
    }
    __syncthreads();

    const unsigned short* W1e = W1T + (size_t)e * H_DIM * D_DIM;
    unsigned int uoff = (unsigned int)(((l & 7) ^ (l >> 3)) * 8);
    unsigned int srcB[8];
    int nrow = ntile * BN + w * 64 + (l >> 3);
#pragma unroll
    for (int c = 0; c < 8; ++c)
        srcB[c] = (unsigned int)((nrow + 8 * c) * D_DIM) + uoff;
    unsigned int abase[8];
#pragma unroll
    for (int mf = 0; mf < 8; ++mf)
        abase[mf] = (unsigned int)toksS[mf * 16 + (l & 15)] * D_DIM
                  + (unsigned int)((l >> 4) * 8);

    f32x4 acc[8][4];
#pragma unroll
    for (int i = 0; i < 8; ++i)
#pragma unroll
        for (int j = 0; j < 4; ++j) acc[i][j] = (f32x4){0.f, 0.f, 0.f, 0.f};

    char* dstbase = (char*)(&Bs[0][0]) + (size_t)w * 8192;
    const char* srcbase = (const char*)W1e;

    // prologue: stage buf 0 (kc = 0)
#pragma unroll
    for (int c = 0; c < 8; ++c)
        async_cp16(srcbase + (size_t)srcB[c] * 2, dstbase + c * 1024);
    __syncthreads();

    const int NT = D_DIM / BK;   // 8
    for (int kc = 0; kc < NT; ++kc) {
        int cur = kc & 1;
        if (kc + 1 < NT) {
            char* db = dstbase + (cur ^ 1) * (BN * BK * 2);
            size_t ko = (size_t)(kc + 1) * BK * 2;
#pragma unroll
            for (int c = 0; c < 8; ++c)
                async_cp16(srcbase + (size_t)srcB[c] * 2 + ko, db + c * 1024);
        }
        const unsigned short* Bc = &Bs[cur][0];
#pragma unroll
        for (int ks = 0; ks < 2; ++ks) {
            bf16x8 av[8];
#pragma unroll
            for (int mf = 0; mf < 8; ++mf)
                av[mf] = *(const bf16x8*)(xb + abase[mf] + kc * 64 + ks * 32);
            bf16x8 bv[4];
            unsigned int u = (unsigned int)((ks * 4 + (l >> 4)) ^ (l & 7));
#pragma unroll
            for (int nf = 0; nf < 4; ++nf) {
                int nloc = w * 64 + nf * 16 + (l & 15);
                bv[nf] = *(const bf16x8*)(Bc + nloc * 64 + u * 8);
            }
#pragma unroll
            for (int mf = 0; mf < 8; ++mf)
#pragma unroll
                for (int nf = 0; nf < 4; ++nf)
                    acc[mf][nf] = __builtin_amdgcn_mfma_f32_16x16x32_bf16(
                        av[mf], bv[nf], acc[mf][nf], 0, 0, 0);
        }
        __syncthreads();
    }

    // epilogue: bias + gelu + gate, store bf16
    float twr[32];
#pragma unroll
    for (int mf = 0; mf < 8; ++mf)
#pragma unroll
        for (int r = 0; r < 4; ++r)
            twr[mf * 4 + r] = twS[mf * 16 + (l >> 4) * 4 + r];
    const float* b1e = b1 + (size_t)e * H_DIM + ntile * BN;
#pragma unroll
    for (int nf = 0; nf < 4; ++nf) {
        int col = w * 64 + nf * 16 + (l & 15);
        float b1v = b1e[col];
#pragma unroll
        for (int mf = 0; mf < 8; ++mf) {
#pragma unroll
            for (int r = 0; r < 4; ++r) {
                int row = mf * 16 + (l >> 4) * 4 + r;
                int gr = mt * BM + row;
                if (gr < cnt) {
                    float hv = twr[mf * 4 + r] * gelu_f(acc[mf][nf][r] + b1v);
                    hdn[(size_t)(base + gr) * H_DIM + ntile * BN + col] = f2b(hv);
                }
            }
        }
    }
}

// ---------------- pass 2: out[tok] += hdn @ W2T ----------------------------
__global__ __launch_bounds__(256, 2) void gemm2_kernel(
        const unsigned short* __restrict__ hdn,   // [2*ntok][2048] bf16
        const unsigned short* __restrict__ W2T,   // [E][512][2048] bf16
        const int* __restrict__ lists,
        const int* __restrict__ cb,
        float* __restrict__ out,
        int ntok) {
    int bid = blockIdx.x;
    int e = bid & 7;
    int rest = bid >> 3;
    int ntile = rest & 1;          // 512/256
    int mt = rest >> 1;
    int cnt = cb[e];
    if (mt * BM >= cnt) return;
    int base = cb[8 + e];

    __shared__ unsigned short Bs[2][BN * BK];
    __shared__ int toksS[BM];

    int tid = threadIdx.x;
    int l = tid & 63, w = tid >> 6;

    if (tid < BM) {
        int idx = mt * BM + tid;
        int entry = (idx < cnt) ? lists[(size_t)e * ntok + idx] : -1;
        toksS[tid] = (entry >= 0) ? (entry >> 1) : 0;
    }
    __syncthreads();

    const unsigned short* W2e = W2T + (size_t)e * D_DIM * H_DIM;
    unsigned int uoff = (unsigned int)(((l & 7) ^ (l >> 3)) * 8);
    unsigned int srcB[8];
    int nrow = ntile * BN + w * 64 + (l >> 3);
#pragma unroll
    for (int c = 0; c < 8; ++c)
        srcB[c] = (unsigned int)((nrow + 8 * c) * H_DIM) + uoff;
    int hlimit = 2 * ntok - 1;
    unsigned int abase[8];
#pragma unroll
    for (int mf = 0; mf < 8; ++mf) {
        int row = base + mt * BM + mf * 16 + (l & 15);
        row = (row > hlimit) ? hlimit : row;
        abase[mf] = (unsigned int)row * H_DIM + (unsigned int)((l >> 4) * 8);
    }

    f32x4 acc[8][4];
#pragma unroll
    for (int i = 0; i < 8; ++i)
#pragma unroll
        for (int j = 0; j < 4; ++j) acc[i][j] = (f32x4){0.f, 0.f, 0.f, 0.f};

    char* dstbase = (char*)(&Bs[0][0]) + (size_t)w * 8192;
    const char* srcbase = (const char*)W2e;

#pragma unroll
    for (int c = 0; c < 8; ++c)
        async_cp16(srcbase + (size_t)srcB[c] * 2, dstbase + c * 1024);
    __syncthreads();

    const int NT = H_DIM / BK;   // 32
    for (int kc = 0; kc < NT; ++kc) {
        int cur = kc & 1;
        if (kc + 1 < NT) {
            char* db = dstbase + (cur ^ 1) * (BN * BK * 2);
            size_t ko = (size_t)(kc + 1) * BK * 2;
#pragma unroll
            for (int c = 0; c < 8; ++c)
                async_cp16(srcbase + (size_t)srcB[c] * 2 + ko, db + c * 1024);
        }
        const unsigned short* Bc = &Bs[cur][0];
#pragma unroll
        for (int ks = 0; ks < 2; ++ks) {
            bf16x8 av[8];
#pragma unroll
            for (int mf = 0; mf < 8; ++mf)
                av[mf] = *(const bf16x8*)(hdn + abase[mf] + kc * 64 + ks * 32);
            bf16x8 bv[4];
            unsigned int u = (unsigned int)((ks * 4 + (l >> 4)) ^ (l & 7));
#pragma unroll
            for (int nf = 0; nf < 4; ++nf) {
                int nloc = w * 64 + nf * 16 + (l & 15);
                bv[nf] = *(const bf16x8*)(Bc + nloc * 64 + u * 8);
            }
#pragma unroll
            for (int mf = 0; mf < 8; ++mf)
#pragma unroll
                for (int nf = 0; nf < 4; ++nf)
                    acc[mf][nf] = __builtin_amdgcn_mfma_f32_16x16x32_bf16(
                        av[mf], bv[nf], acc[mf][nf], 0, 0, 0);
        }
        __syncthreads();
    }

    // epilogue: scatter atomicAdd (b2+gate handled by bias_gate_kernel)
    int tokr[32];
#pragma unroll
    for (int mf = 0; mf < 8; ++mf)
#pragma unroll
        for (int r = 0; r < 4; ++r)
            tokr[mf * 4 + r] = toksS[mf * 16 + (l >> 4) * 4 + r];
#pragma unroll
    for (int mf = 0; mf < 8; ++mf) {
#pragma unroll
        for (int r = 0; r < 4; ++r) {
            int row = mf * 16 + (l >> 4) * 4 + r;
            int gr = mt * BM + row;
            if (gr < cnt) {
                float* op = out + (size_t)tokr[mf * 4 + r] * D_DIM;
#pragma unroll
                for (int nf = 0; nf < 4; ++nf) {
                    int col = ntile * BN + w * 64 + nf * 16 + (l & 15);
                    atomicAdd(op + col, acc[mf][nf][r]);
                }
            }
        }
    }
}

// ================= fused fallback (small workspace) ========================
#define FBT 64
#define FKC 64
#define FHC 64
#define FTPB 512

__global__ __launch_bounds__(FTPB) void moe_fused_fallback(
        const float* __restrict__ x,
        const float* __restrict__ W1, const float* __restrict__ b1,
        const float* __restrict__ W2, const float* __restrict__ b2,
        const float* __restrict__ gate_w,
        const int* __restrict__ lists, const int* __restrict__ counts,
        float* __restrict__ out, int ntok, int tiles) {
    __shared__ __align__(16) float ldsA[FBT][FKC + 4];
    __shared__ __align__(16) float ldsB[FKC][FHC + 4];
    __shared__ int   toks[FBT];
    __shared__ float tw[FBT];
    int e = blockIdx.x / tiles;
    int tile = blockIdx.x % tiles;
    int cnt = counts[e];
    if (tile * FBT >= cnt) return;
    int tid = threadIdx.x;
    int srow = tid >> 3, scol = (tid & 7) * 8;
    int tg2 = tid >> 4, sg4 = tid & 15;
    if (tid < FBT) {
        int idx = tile * FBT + tid;
        int entry = (idx < cnt) ? lists[(size_t)e * ntok + idx] : -1;
        toks[tid] = (entry >= 0) ? (entry >> 1) : 0;
        tw[tid]   = (entry >= 0) ? gate_w[entry] : 0.0f;
    }
    __syncthreads();
    float yacc[2][32];
#pragma unroll
    for (int p = 0; p < 2; ++p)
#pragma unroll
        for (int i = 0; i < 32; ++i) yacc[p][i] = 0.0f;
    const float* W1e = W1 + (size_t)e * D_DIM * H_DIM;
    const float* W2e = W2 + (size_t)e * H_DIM * D_DIM;
    const float* b1e = b1 + (size_t)e * H_DIM;
    int t0 = tg2, t1 = tg2 + 32;
    for (int hc = 0; hc < H_DIM / FHC; ++hc) {
        float pre[2][4];
#pragma unroll
        for (int p = 0; p < 2; ++p)
#pragma unroll
            for (int j = 0; j < 4; ++j) pre[p][j] = 0.0f;
        for (int kc = 0; kc < D_DIM / FKC; ++kc) {
            __syncthreads();
            {
                const float* src = x + (size_t)toks[srow] * D_DIM + kc * FKC + scol;
                *(float4*)&ldsA[srow][scol]     = *(const float4*)(src);
                *(float4*)&ldsA[srow][scol + 4] = *(const float4*)(src + 4);
                const float* ws1 = W1e + (size_t)(kc * FKC + srow) * H_DIM + hc * FHC + scol;
                *(float4*)&ldsB[srow][scol]     = *(const float4*)(ws1);
                *(float4*)&ldsB[srow][scol + 4] = *(const float4*)(ws1 + 4);
            }
            __syncthreads();
#pragma unroll
            for (int k = 0; k < FKC; ++k) {
                float a0 = ldsA[t0][k], a1 = ldsA[t1][k];
                const float4 b4 = *(const float4*)&ldsB[k][sg4 * 4];
                pre[0][0] = fmaf(a0, b4.x, pre[0][0]);
                pre[0][1] = fmaf(a0, b4.y, pre[0][1]);
                pre[0][2] = fmaf(a0, b4.z, pre[0][2]);
                pre[0][3] = fmaf(a0, b4.w, pre[0][3]);
                pre[1][0] = fmaf(a1, b4.x, pre[1][0]);
                pre[1][1] = fmaf(a1, b4.y, pre[1][1]);
                pre[1][2] = fmaf(a1, b4.z, pre[1][2]);
                pre[1][3] = fmaf(a1, b4.w, pre[1][3]);
            }
        }
        __syncthreads();
        {
            const float* b1p = b1e + hc * FHC + sg4 * 4;
            float4 h0, h1;
            h0.x = gelu_f(pre[0][0] + b1p[0]); h0.y = gelu_f(pre[0][1] + b1p[1]);
            h0.z = gelu_f(pre[0][2] + b1p[2]); h0.w = gelu_f(pre[0][3] + b1p[3]);
            h1.x = gelu_f(pre[1][0] + b1p[0]); h1.y = gelu_f(pre[1][1] + b1p[1]);
            h1.z = gelu_f(pre[1][2] + b1p[2]); h1.w = gelu_f(pre[1][3] + b1p[3]);
            *(float4*)&ldsA[t0][sg4 * 4] = h0;
            *(float4*)&ldsA[t1][sg4 * 4] = h1;
        }
        for (int dt = 0; dt < 8; ++dt) {
            __syncthreads();
            {
                const float* ws2 = W2e + (size_t)(hc * FHC + srow) * D_DIM + dt * 64 + scol;
                *(float4*)&ldsB[srow][scol]     = *(const float4*)(ws2);
                *(float4*)&ldsB[srow][scol + 4] = *(const float4*)(ws2 + 4);
            }
            __syncthreads();
#pragma unroll
            for (int hh = 0; hh < FHC; ++hh) {
                float a0 = ldsA[t0][hh], a1 = ldsA[t1][hh];
                const float4 b4 = *(const float4*)&ldsB[hh][sg4 * 4];
                yacc[0][dt * 4 + 0] = fmaf(a0, b4.x, yacc[0][dt * 4 + 0]);
                yacc[0][dt * 4 + 1] = fmaf(a0, b4.y, yacc[0][dt * 4 + 1]);
                yacc[0][dt * 4 + 2] = fmaf(a0, b4.z, yacc[0][dt * 4 + 2]);
                yacc[0][dt * 4 + 3] = fmaf(a0, b4.w, yacc[0][dt * 4 + 3]);
                yacc[1][dt * 4 + 0] = fmaf(a1, b4.x, yacc[1][dt * 4 + 0]);
                yacc[1][dt * 4 + 1] = fmaf(a1, b4.y, yacc[1][dt * 4 + 1]);
                yacc[1][dt * 4 + 2] = fmaf(a1, b4.z, yacc[1][dt * 4 + 2]);
                yacc[1][dt * 4 + 3] = fmaf(a1, b4.w, yacc[1][dt * 4 + 3]);
            }
        }
    }
    const float* b2e = b2 + (size_t)e * D_DIM;
#pragma unroll
    for (int p = 0; p < 2; ++p) {
        int slot = (p == 0) ? t0 : t1;
        if (tile * FBT + slot < cnt) {
            float wv = tw[slot];
            float* op = out + (size_t)toks[slot] * D_DIM;
#pragma unroll
            for (int dt = 0; dt < 8; ++dt)
#pragma unroll
                for (int j = 0; j < 4; ++j) {
                    int d = dt * 64 + sg4 * 4 + j;
                    atomicAdd(&op[d], wv * (yacc[p][dt * 4 + j] + b2e[d]));
                }
        }
    }
}

// ===========================================================================
extern "C" void kernel_launch(void* const* d_in, const int* in_sizes, int n_in,
                              void* d_out, int out_size, void* d_ws, size_t ws_size,
                              hipStream_t stream) {
    const float* x  = (const float*)d_in[0];
    const float* Wr = (const float*)d_in[1];
    const float* W1 = (const float*)d_in[2];
    const float* b1 = (const float*)d_in[3];
    const float* W2 = (const float*)d_in[4];
    const float* b2 = (const float*)d_in[5];
    float* out = (float*)d_out;
    int ntok = in_sizes[0] / D_DIM;   // 16384

    size_t off_route = 256;
    size_t off_gate  = off_route + (size_t)ntok * 4;
    size_t off_lists = off_gate + (size_t)2 * ntok * 4;
    size_t off_xb    = off_lists + (size_t)NEXP * ntok * 4;
    size_t off_w1t   = off_xb + (size_t)ntok * D_DIM * 2;
    size_t off_w2t   = off_w1t + (size_t)NEXP * D_DIM * H_DIM * 2;
    size_t off_hdn   = off_w2t + (size_t)NEXP * D_DIM * H_DIM * 2;
    size_t need      = off_hdn + (size_t)2 * ntok * H_DIM * 2;

    int*   cb     = (int*)d_ws;
    int*   route  = (int*)((char*)d_ws + off_route);
    float* gate_w = (float*)((char*)d_ws + off_gate);
    int*   lists  = (int*)((char*)d_ws + off_lists);

    if (ws_size >= need) {
        unsigned short* xb  = (unsigned short*)((char*)d_ws + off_xb);
        unsigned short* W1T = (unsigned short*)((char*)d_ws + off_w1t);
        unsigned short* W2T = (unsigned short*)((char*)d_ws + off_w2t);
        unsigned short* hdn = (unsigned short*)((char*)d_ws + off_hdn);

        int n8 = ntok * D_DIM / 8;
        convert_x_kernel<<<(n8 + 255) / 256, 256, 0, stream>>>(x, xb, n8);
        transpose_conv_kernel<<<dim3(H_DIM / 64, D_DIM / 64, NEXP), 256, 0, stream>>>(
            W1, W1T, D_DIM, H_DIM);
        transpose_conv_kernel<<<dim3(D_DIM / 64, H_DIM / 64, NEXP), 256, 0, stream>>>(
            W2, W2T, H_DIM, D_DIM);
        router_kernel<<<(ntok + 3) / 4, 256, 0, stream>>>(
            x, Wr, gate_w, route, ntok);
        lists_kernel<<<NEXP, 256, 0, stream>>>(route, lists, cb, ntok);
        prefix_kernel<<<1, 64, 0, stream>>>(cb);
        bias_gate_kernel<<<(ntok + 3) / 4, 256, 0, stream>>>(
            route, gate_w, b2, out, ntok);
        int mtiles = ntok / BM;   // 128
        gemm1_kernel<<<NEXP * (H_DIM / BN) * mtiles, 256, 0, stream>>>(
            xb, W1T, b1, gate_w, lists, cb, hdn, ntok);
        gemm2_kernel<<<NEXP * (D_DIM / BN) * mtiles, 256, 0, stream>>>(
            hdn, W2T, lists, cb, out, ntok);
    } else {
        hipMemsetAsync(d_out, 0, (size_t)out_size * sizeof(float), stream);
        router_kernel<<<(ntok + 3) / 4, 256, 0, stream>>>(
            x, Wr, gate_w, route, ntok);
        lists_kernel<<<NEXP, 256, 0, stream>>>(route, lists, cb, ntok);
        prefix_kernel<<<1, 64, 0, stream>>>(cb);
        int tiles = (ntok + FBT - 1) / FBT;
        moe_fused_fallback<<<NEXP * tiles, FTPB, 0, stream>>>(
            x, W1, b1, W2, b2, gate_w, lists, cb, out, ntok, tiles);
    }
}

// Round 4
// 359.868 us; speedup vs baseline: 11.8388x; 1.8386x over previous
//
#include <hip/hip_runtime.h>
#include <math.h>

#define D_DIM 512
#define H_DIM 2048
#define NEXP  8

typedef __bf16 bf16x8 __attribute__((ext_vector_type(8)));
typedef float  f32x4  __attribute__((ext_vector_type(4)));

__device__ __forceinline__ unsigned short f2b(float f) {
    unsigned int u = __float_as_uint(f);
    unsigned int r = (u + 0x7FFFu + ((u >> 16) & 1u)) >> 16;
    return (unsigned short)r;
}

// exact-ish gelu: erf via Abramowitz-Stegun 7.1.26 (|err| < 1.5e-7)
__device__ __forceinline__ float gelu_f(float v) {
    float z = fabsf(v) * 0.70710678118654752440f;
    float t = __builtin_amdgcn_rcpf(fmaf(0.3275911f, z, 1.0f));
    float poly = t * (0.254829592f +
                 t * (-0.284496736f +
                 t * (1.421413741f +
                 t * (-1.453152027f +
                 t * 1.061405429f))));
    float er = 1.0f - poly * __expf(-z * z);
    er = (v < 0.0f) ? -er : er;
    return 0.5f * v * (1.0f + er);
}

__device__ __forceinline__ void async_cp16(const void* g, void* l) {
    __builtin_amdgcn_global_load_lds(
        (const __attribute__((address_space(1))) unsigned int*)g,
        (__attribute__((address_space(3))) unsigned int*)l, 16, 0, 0);
}

// ---------------- converts -------------------------------------------------
__global__ void convert_x_kernel(const float* __restrict__ in,
                                 unsigned short* __restrict__ out, int n8) {
    int i = blockIdx.x * blockDim.x + threadIdx.x;
    if (i >= n8) return;
    const float4* p = (const float4*)(in + (size_t)i * 8);
    float4 a = p[0], b = p[1];
    unsigned short r[8] = {f2b(a.x), f2b(a.y), f2b(a.z), f2b(a.w),
                           f2b(b.x), f2b(b.y), f2b(b.z), f2b(b.w)};
    *(uint4*)(out + (size_t)i * 8) = *(const uint4*)r;
}

// in [e][R][C] f32 -> out [e][C][R] bf16
__global__ void transpose_conv_kernel(const float* __restrict__ in,
                                      unsigned short* __restrict__ out,
                                      int R, int C) {
    __shared__ unsigned short tile[64][72];
    int e = blockIdx.z;
    const float* ine = in + (size_t)e * R * C;
    unsigned short* oute = out + (size_t)e * C * R;
    int r0 = blockIdx.y * 64, c0 = blockIdx.x * 64;
    int tid = threadIdx.x;
#pragma unroll
    for (int rd = 0; rd < 4; ++rd) {
        int r = (tid >> 4) + rd * 16;
        int c = (tid & 15) * 4;
        float4 v = *(const float4*)&ine[(size_t)(r0 + r) * C + c0 + c];
        tile[c + 0][r] = f2b(v.x);
        tile[c + 1][r] = f2b(v.y);
        tile[c + 2][r] = f2b(v.z);
        tile[c + 3][r] = f2b(v.w);
    }
    __syncthreads();
    int cc = tid >> 2, rc = (tid & 3) * 16;
    unsigned short* op = oute + (size_t)(c0 + cc) * R + r0 + rc;
    *(uint4*)(op)     = *(const uint4*)&tile[cc][rc];
    *(uint4*)(op + 8) = *(const uint4*)&tile[cc][rc + 8];
}

// ---------------- router: per-token top2+softmax only (NO atomics) ---------
__global__ void router_kernel(const float* __restrict__ x,
                              const float* __restrict__ Wr,
                              float* __restrict__ gate_w,
                              int* __restrict__ route,
                              int ntok) {
    int wid  = (blockIdx.x * blockDim.x + threadIdx.x) >> 6;
    int lane = threadIdx.x & 63;
    if (wid >= ntok) return;
    const float* xr = x + (size_t)wid * D_DIM;
    float acc[NEXP];
#pragma unroll
    for (int e = 0; e < NEXP; ++e) acc[e] = 0.0f;
#pragma unroll
    for (int it = 0; it < D_DIM / 64; ++it) {
        int d = it * 64 + lane;
        float xv = xr[d];
        const float* wr = Wr + d * NEXP;
#pragma unroll
        for (int e = 0; e < NEXP; ++e) acc[e] = fmaf(xv, wr[e], acc[e]);
    }
#pragma unroll
    for (int off = 32; off >= 1; off >>= 1) {
#pragma unroll
        for (int e = 0; e < NEXP; ++e) acc[e] += __shfl_xor(acc[e], off);
    }
    if (lane == 0) {
        int i0 = 0;
#pragma unroll
        for (int e = 1; e < NEXP; ++e) if (acc[e] > acc[i0]) i0 = e;
        int i1 = (i0 == 0) ? 1 : 0;
#pragma unroll
        for (int e = 0; e < NEXP; ++e) {
            if (e != i0 && acc[e] > acc[i1]) i1 = e;
        }
        float v0 = acc[i0], v1 = acc[i1];
        float ee = expf(v1 - v0);
        float inv = 1.0f / (1.0f + ee);
        int t = wid;
        gate_w[2 * t]     = inv;
        gate_w[2 * t + 1] = ee * inv;
        route[t] = i0 | (i1 << 8);
    }
}

// ---------------- deterministic per-expert stream compaction ---------------
__global__ void lists_kernel(const int* __restrict__ route,
                             int* __restrict__ lists,
                             int* __restrict__ cb,
                             int ntok) {
    __shared__ int wave_off[4];
    int e = blockIdx.x;
    int tid = threadIdx.x;
    int lane = tid & 63, w = tid >> 6;
    int running = 0;
    for (int c0 = 0; c0 < ntok; c0 += 256) {
        int t = c0 + tid;
        int rt = (t < ntok) ? route[t] : -1;
        int e0 = rt & 255, e1 = (rt >> 8) & 255;
        bool p1 = (e1 == e) && (rt >= 0);
        bool p  = ((e0 == e) && (rt >= 0)) || p1;
        unsigned long long mask = __ballot(p);
        int mypos = __popcll(mask & ((1ull << lane) - 1ull));
        int wcnt  = __popcll(mask);
        if (lane == 0) wave_off[w] = wcnt;
        __syncthreads();
        int wbase = 0;
#pragma unroll
        for (int i = 0; i < 4; ++i) if (i < w) wbase += wave_off[i];
        int total = wave_off[0] + wave_off[1] + wave_off[2] + wave_off[3];
        if (p) lists[(size_t)e * ntok + running + wbase + mypos] = 2 * t + (p1 ? 1 : 0);
        running += total;
        __syncthreads();
    }
    if (tid == 0) cb[e] = running;
}

__global__ void prefix_kernel(int* cb) {
    if (threadIdx.x == 0 && blockIdx.x == 0) {
        int s = 0;
#pragma unroll
        for (int e = 0; e < NEXP; ++e) { cb[8 + e] = s; s += cb[e]; }
    }
}

// out[tok] = w0*b2[e0] + w1*b2[e1]
__global__ void bias_gate_kernel(const int* __restrict__ route,
                                 const float* __restrict__ gate_w,
                                 const float* __restrict__ b2,
                                 float* __restrict__ out, int ntok) {
    int t = blockIdx.x * 4 + (threadIdx.x >> 6);
    int lane = threadIdx.x & 63;
    if (t >= ntok) return;
    int rt = route[t];
    int e0 = rt & 255, e1 = (rt >> 8) & 255;
    float w0 = gate_w[2 * t], w1 = gate_w[2 * t + 1];
    const float4* p0 = (const float4*)(b2 + (size_t)e0 * D_DIM);
    const float4* p1 = (const float4*)(b2 + (size_t)e1 * D_DIM);
    float4* po = (float4*)(out + (size_t)t * D_DIM);
#pragma unroll
    for (int j = 0; j < 2; ++j) {
        float4 a = p0[lane * 2 + j], b = p1[lane * 2 + j];
        float4 r;
        r.x = w0 * a.x + w1 * b.x;
        r.y = w0 * a.y + w1 * b.y;
        r.z = w0 * a.z + w1 * b.z;
        r.w = w0 * a.w + w1 * b.w;
        po[lane * 2 + j] = r;
    }
}

// ============ m97-style 128x128 BK=64 grouped GEMMs ========================
// 4 waves (2Mx2N), wave tile 64x64 = acc[4][4] of 16x16x32 frags.
// A and B both staged via global_load_lds w16; A uses per-lane gather source.
// LDS row layout: row r (128B = 8 chunks of 16B); chunk slot s holds global
// chunk s ^ (r&7)  (XOR swizzle -> conflict-free ds_read_b128).

// ---------------- pass 1: hdn = gate * gelu(Xg @ W1T^T + b1) ---------------
__global__ __launch_bounds__(256, 2) void gemm1_kernel(
        const unsigned short* __restrict__ xb,    // [ntok][512] bf16
        const unsigned short* __restrict__ W1T,   // [E][2048][512] bf16
        const float* __restrict__ b1,             // [E][2048]
        const float* __restrict__ gate_w,
        const int* __restrict__ lists,
        const int* __restrict__ cb,               // counts[0..7] bases[8..15]
        unsigned short* __restrict__ hdn,         // [2*ntok+128][2048] bf16
        int ntok) {
    int bid = blockIdx.x;
    int e = bid & 7;                 // expert -> XCD pin
    int rest = bid >> 3;
    int ntile = rest & 15;           // 2048/128
    int mt = rest >> 4;
    int cnt = cb[e];
    if (mt * 128 >= cnt) return;
    int base = cb[8 + e];

    __shared__ unsigned short As[2][8192];   // 16 KB per buf
    __shared__ unsigned short Bs[2][8192];
    __shared__ int   toksS[128];
    __shared__ float twS[128];

    int tid = threadIdx.x;
    int l = tid & 63, w = tid >> 6;
    int wm = (w & 1) * 64, wn = (w >> 1) * 64;

    if (tid < 128) {
        int idx = mt * 128 + tid;
        int entry = (idx < cnt) ? lists[(size_t)e * ntok + idx] : -1;
        toksS[tid] = (entry >= 0) ? (entry >> 1) : 0;
        twS[tid]   = (entry >= 0) ? gate_w[entry] : 0.0f;
    }
    __syncthreads();

    const char* Aglob[4];
    const char* Bglob[4];
    {
        int swz = ((l & 7) ^ (l >> 3)) * 16;
        const char* W1e = (const char*)(W1T + (size_t)e * H_DIM * D_DIM);
#pragma unroll
        for (int c = 0; c < 4; ++c) {
            int row = (w * 4 + c) * 8 + (l >> 3);       // row&7 == l>>3
            Aglob[c] = (const char*)xb + (size_t)toksS[row] * 1024 + swz;
            Bglob[c] = W1e + (size_t)(ntile * 128 + row) * 1024 + swz;
        }
    }

    f32x4 acc[4][4];
#pragma unroll
    for (int i = 0; i < 4; ++i)
#pragma unroll
        for (int j = 0; j < 4; ++j) acc[i][j] = (f32x4){0.f, 0.f, 0.f, 0.f};

    // prologue stage buf0 (kc=0)
#pragma unroll
    for (int c = 0; c < 4; ++c) {
        async_cp16(Aglob[c], (char*)&As[0][0] + (w * 4 + c) * 1024);
        async_cp16(Bglob[c], (char*)&Bs[0][0] + (w * 4 + c) * 1024);
    }
    __syncthreads();

    for (int kc = 0; kc < 8; ++kc) {
        int cur = kc & 1;
        if (kc + 1 < 8) {
            int ko = (kc + 1) * 128;
#pragma unroll
            for (int c = 0; c < 4; ++c) {
                async_cp16(Aglob[c] + ko, (char*)&As[cur ^ 1][0] + (w * 4 + c) * 1024);
                async_cp16(Bglob[c] + ko, (char*)&Bs[cur ^ 1][0] + (w * 4 + c) * 1024);
            }
        }
        const char* Ab = (const char*)&As[cur][0];
        const char* Bb = (const char*)&Bs[cur][0];
#pragma unroll
        for (int ks = 0; ks < 2; ++ks) {
            int g = ks * 4 + (l >> 4);
            bf16x8 av[4], bv[4];
#pragma unroll
            for (int mf = 0; mf < 4; ++mf) {
                int m = wm + mf * 16 + (l & 15);
                av[mf] = *(const bf16x8*)(Ab + m * 128 + ((g ^ (m & 7)) * 16));
            }
#pragma unroll
            for (int nf = 0; nf < 4; ++nf) {
                int n = wn + nf * 16 + (l & 15);
                bv[nf] = *(const bf16x8*)(Bb + n * 128 + ((g ^ (n & 7)) * 16));
            }
#pragma unroll
            for (int mf = 0; mf < 4; ++mf)
#pragma unroll
                for (int nf = 0; nf < 4; ++nf)
                    acc[mf][nf] = __builtin_amdgcn_mfma_f32_16x16x32_bf16(
                        av[mf], bv[nf], acc[mf][nf], 0, 0, 0);
        }
        __syncthreads();
    }

    // ---- epilogue: gelu+gate -> LDS (swizzled) -> coalesced 16B stores ----
    float twr[4][4];
#pragma unroll
    for (int mf = 0; mf < 4; ++mf)
#pragma unroll
        for (int r = 0; r < 4; ++r)
            twr[mf][r] = twS[wm + mf * 16 + (l >> 4) * 4 + r];
    const float* b1e = b1 + (size_t)e * H_DIM + ntile * 128;
    float b1v[4];
#pragma unroll
    for (int nf = 0; nf < 4; ++nf)
        b1v[nf] = b1e[wn + nf * 16 + (l & 15)];

    char* Lo = (char*)&As[0][0];     // 32 KB out tile: [128 rows][256 B]
#pragma unroll
    for (int mf = 0; mf < 4; ++mf) {
#pragma unroll
        for (int nf = 0; nf < 4; ++nf) {
#pragma unroll
            for (int r = 0; r < 4; ++r) {
                int row = wm + mf * 16 + (l >> 4) * 4 + r;
                int col = wn + nf * 16 + (l & 15);
                float hv = twr[mf][r] * gelu_f(acc[mf][nf][r] + b1v[nf]);
                int byte = row * 256 + ((col * 2) ^ (((row >> 2) & 3) << 5));
                *(unsigned short*)(Lo + byte) = f2b(hv);
            }
        }
    }
    __syncthreads();
#pragma unroll
    for (int j = 0; j < 8; ++j) {
        int row = j * 16 + (tid >> 4);
        int c16 = tid & 15;
        uint4 v = *(const uint4*)(Lo + row * 256 + c16 * 16);
        int colchunk = c16 ^ (((row >> 2) & 3) << 1);
        int gr = mt * 128 + row;
        if (gr < cnt)
            *(uint4*)(hdn + (size_t)(base + gr) * H_DIM + ntile * 128 + colchunk * 8) = v;
    }
}

// ---------------- pass 2: out[tok] += hdn @ W2T^T --------------------------
__global__ __launch_bounds__(256, 2) void gemm2_kernel(
        const unsigned short* __restrict__ hdn,   // [2*ntok+128][2048] bf16
        const unsigned short* __restrict__ W2T,   // [E][512][2048] bf16
        const int* __restrict__ lists,
        const int* __restrict__ cb,
        float* __restrict__ out,
        int ntok) {
    int bid = blockIdx.x;
    int e = bid & 7;
    int rest = bid >> 3;
    int ntile = rest & 3;            // 512/128
    int mt = rest >> 2;
    int cnt = cb[e];
    if (mt * 128 >= cnt) return;
    int base = cb[8 + e];

    __shared__ unsigned short As[2][8192];
    __shared__ unsigned short Bs[2][8192];
    __shared__ int toksS[128];

    int tid = threadIdx.x;
    int l = tid & 63, w = tid >> 6;
    int wm = (w & 1) * 64, wn = (w >> 1) * 64;

    if (tid < 128) {
        int idx = mt * 128 + tid;
        int entry = (idx < cnt) ? lists[(size_t)e * ntok + idx] : -1;
        toksS[tid] = (entry >= 0) ? (entry >> 1) : 0;
    }
    __syncthreads();

    const char* Aglob[4];
    const char* Bglob[4];
    {
        int swz = ((l & 7) ^ (l >> 3)) * 16;
        const char* W2e = (const char*)(W2T + (size_t)e * D_DIM * H_DIM);
#pragma unroll
        for (int c = 0; c < 4; ++c) {
            int row = (w * 4 + c) * 8 + (l >> 3);
            Aglob[c] = (const char*)hdn + (size_t)(base + mt * 128 + row) * 4096 + swz;
            Bglob[c] = W2e + (size_t)(ntile * 128 + row) * 4096 + swz;
        }
    }

    f32x4 acc[4][4];
#pragma unroll
    for (int i = 0; i < 4; ++i)
#pragma unroll
        for (int j = 0; j < 4; ++j) acc[i][j] = (f32x4){0.f, 0.f, 0.f, 0.f};

#pragma unroll
    for (int c = 0; c < 4; ++c) {
        async_cp16(Aglob[c], (char*)&As[0][0] + (w * 4 + c) * 1024);
        async_cp16(Bglob[c], (char*)&Bs[0][0] + (w * 4 + c) * 1024);
    }
    __syncthreads();

    for (int kc = 0; kc < 32; ++kc) {
        int cur = kc & 1;
        if (kc + 1 < 32) {
            int ko = (kc + 1) * 128;
#pragma unroll
            for (int c = 0; c < 4; ++c) {
                async_cp16(Aglob[c] + ko, (char*)&As[cur ^ 1][0] + (w * 4 + c) * 1024);
                async_cp16(Bglob[c] + ko, (char*)&Bs[cur ^ 1][0] + (w * 4 + c) * 1024);
            }
        }
        const char* Ab = (const char*)&As[cur][0];
        const char* Bb = (const char*)&Bs[cur][0];
#pragma unroll
        for (int ks = 0; ks < 2; ++ks) {
            int g = ks * 4 + (l >> 4);
            bf16x8 av[4], bv[4];
#pragma unroll
            for (int mf = 0; mf < 4; ++mf) {
                int m = wm + mf * 16 + (l & 15);
                av[mf] = *(const bf16x8*)(Ab + m * 128 + ((g ^ (m & 7)) * 16));
            }
#pragma unroll
            for (int nf = 0; nf < 4; ++nf) {
                int n = wn + nf * 16 + (l & 15);
                bv[nf] = *(const bf16x8*)(Bb + n * 128 + ((g ^ (n & 7)) * 16));
            }
#pragma unroll
            for (int mf = 0; mf < 4; ++mf)
#pragma unroll
                for (int nf = 0; nf < 4; ++nf)
                    acc[mf][nf] = __builtin_amdgcn_mfma_f32_16x16x32_bf16(
                        av[mf], bv[nf], acc[mf][nf], 0, 0, 0);
        }
        __syncthreads();
    }

    // epilogue: masked atomic scatter (bias handled by bias_gate_kernel)
#pragma unroll
    for (int mf = 0; mf < 4; ++mf) {
#pragma unroll
        for (int r = 0; r < 4; ++r) {
            int rl = wm + mf * 16 + (l >> 4) * 4 + r;
            int gr = mt * 128 + rl;
            if (gr < cnt) {
                float* op = out + (size_t)toksS[rl] * D_DIM + ntile * 128 + wn;
#pragma unroll
                for (int nf = 0; nf < 4; ++nf)
                    atomicAdd(op + nf * 16 + (l & 15), acc[mf][nf][r]);
            }
        }
    }
}

// ================= fused fallback (small workspace) ========================
#define FBT 64
#define FKC 64
#define FHC 64
#define FTPB 512

__global__ __launch_bounds__(FTPB) void moe_fused_fallback(
        const float* __restrict__ x,
        const float* __restrict__ W1, const float* __restrict__ b1,
        const float* __restrict__ W2, const float* __restrict__ b2,
        const float* __restrict__ gate_w,
        const int* __restrict__ lists, const int* __restrict__ counts,
        float* __restrict__ out, int ntok, int tiles) {
    __shared__ __align__(16) float ldsA[FBT][FKC + 4];
    __shared__ __align__(16) float ldsB[FKC][FHC + 4];
    __shared__ int   toks[FBT];
    __shared__ float tw[FBT];
    int e = blockIdx.x / tiles;
    int tile = blockIdx.x % tiles;
    int cnt = counts[e];
    if (tile * FBT >= cnt) return;
    int tid = threadIdx.x;
    int srow = tid >> 3, scol = (tid & 7) * 8;
    int tg2 = tid >> 4, sg4 = tid & 15;
    if (tid < FBT) {
        int idx = tile * FBT + tid;
        int entry = (idx < cnt) ? lists[(size_t)e * ntok + idx] : -1;
        toks[tid] = (entry >= 0) ? (entry >> 1) : 0;
        tw[tid]   = (entry >= 0) ? gate_w[entry] : 0.0f;
    }
    __syncthreads();
    float yacc[2][32];
#pragma unroll
    for (int p = 0; p < 2; ++p)
#pragma unroll
        for (int i = 0; i < 32; ++i) yacc[p][i] = 0.0f;
    const float* W1e = W1 + (size_t)e * D_DIM * H_DIM;
    const float* W2e = W2 + (size_t)e * H_DIM * D_DIM;
    const float* b1e = b1 + (size_t)e * H_DIM;
    int t0 = tg2, t1 = tg2 + 32;
    for (int hc = 0; hc < H_DIM / FHC; ++hc) {
        float pre[2][4];
#pragma unroll
        for (int p = 0; p < 2; ++p)
#pragma unroll
            for (int j = 0; j < 4; ++j) pre[p][j] = 0.0f;
        for (int kc = 0; kc < D_DIM / FKC; ++kc) {
            __syncthreads();
            {
                const float* src = x + (size_t)toks[srow] * D_DIM + kc * FKC + scol;
                *(float4*)&ldsA[srow][scol]     = *(const float4*)(src);
                *(float4*)&ldsA[srow][scol + 4] = *(const float4*)(src + 4);
                const float* ws1 = W1e + (size_t)(kc * FKC + srow) * H_DIM + hc * FHC + scol;
                *(float4*)&ldsB[srow][scol]     = *(const float4*)(ws1);
                *(float4*)&ldsB[srow][scol + 4] = *(const float4*)(ws1 + 4);
            }
            __syncthreads();
#pragma unroll
            for (int k = 0; k < FKC; ++k) {
                float a0 = ldsA[t0][k], a1 = ldsA[t1][k];
                const float4 b4 = *(const float4*)&ldsB[k][sg4 * 4];
                pre[0][0] = fmaf(a0, b4.x, pre[0][0]);
                pre[0][1] = fmaf(a0, b4.y, pre[0][1]);
                pre[0][2] = fmaf(a0, b4.z, pre[0][2]);
                pre[0][3] = fmaf(a0, b4.w, pre[0][3]);
                pre[1][0] = fmaf(a1, b4.x, pre[1][0]);
                pre[1][1] = fmaf(a1, b4.y, pre[1][1]);
                pre[1][2] = fmaf(a1, b4.z, pre[1][2]);
                pre[1][3] = fmaf(a1, b4.w, pre[1][3]);
            }
        }
        __syncthreads();
        {
            const float* b1p = b1e + hc * FHC + sg4 * 4;
            float4 h0, h1;
            h0.x = gelu_f(pre[0][0] + b1p[0]); h0.y = gelu_f(pre[0][1] + b1p[1]);
            h0.z = gelu_f(pre[0][2] + b1p[2]); h0.w = gelu_f(pre[0][3] + b1p[3]);
            h1.x = gelu_f(pre[1][0] + b1p[0]); h1.y = gelu_f(pre[1][1] + b1p[1]);
            h1.z = gelu_f(pre[1][2] + b1p[2]); h1.w = gelu_f(pre[1][3] + b1p[3]);
            *(float4*)&ldsA[t0][sg4 * 4] = h0;
            *(float4*)&ldsA[t1][sg4 * 4] = h1;
        }
        for (int dt = 0; dt < 8; ++dt) {
            __syncthreads();
            {
                const float* ws2 = W2e + (size_t)(hc * FHC + srow) * D_DIM + dt * 64 + scol;
                *(float4*)&ldsB[srow][scol]     = *(const float4*)(ws2);
                *(float4*)&ldsB[srow][scol + 4] = *(const float4*)(ws2 + 4);
            }
            __syncthreads();
#pragma unroll
            for (int hh = 0; hh < FHC; ++hh) {
                float a0 = ldsA[t0][hh], a1 = ldsA[t1][hh];
                const float4 b4 = *(const float4*)&ldsB[hh][sg4 * 4];
                yacc[0][dt * 4 + 0] = fmaf(a0, b4.x, yacc[0][dt * 4 + 0]);
                yacc[0][dt * 4 + 1] = fmaf(a0, b4.y, yacc[0][dt * 4 + 1]);
                yacc[0][dt * 4 + 2] = fmaf(a0, b4.z, yacc[0][dt * 4 + 2]);
                yacc[0][dt * 4 + 3] = fmaf(a0, b4.w, yacc[0][dt * 4 + 3]);
                yacc[1][dt * 4 + 0] = fmaf(a1, b4.x, yacc[1][dt * 4 + 0]);
                yacc[1][dt * 4 + 1] = fmaf(a1, b4.y, yacc[1][dt * 4 + 1]);
                yacc[1][dt * 4 + 2] = fmaf(a1, b4.z, yacc[1][dt * 4 + 2]);
                yacc[1][dt * 4 + 3] = fmaf(a1, b4.w, yacc[1][dt * 4 + 3]);
            }
        }
    }
    const float* b2e = b2 + (size_t)e * D_DIM;
#pragma unroll
    for (int p = 0; p < 2; ++p) {
        int slot = (p == 0) ? t0 : t1;
        if (tile * FBT + slot < cnt) {
            float wv = tw[slot];
            float* op = out + (size_t)toks[slot] * D_DIM;
#pragma unroll
            for (int dt = 0; dt < 8; ++dt)
#pragma unroll
                for (int j = 0; j < 4; ++j) {
                    int d = dt * 64 + sg4 * 4 + j;
                    atomicAdd(&op[d], wv * (yacc[p][dt * 4 + j] + b2e[d]));
                }
        }
    }
}

// ===========================================================================
extern "C" void kernel_launch(void* const* d_in, const int* in_sizes, int n_in,
                              void* d_out, int out_size, void* d_ws, size_t ws_size,
                              hipStream_t stream) {
    const float* x  = (const float*)d_in[0];
    const float* Wr = (const float*)d_in[1];
    const float* W1 = (const float*)d_in[2];
    const float* b1 = (const float*)d_in[3];
    const float* W2 = (const float*)d_in[4];
    const float* b2 = (const float*)d_in[5];
    float* out = (float*)d_out;
    int ntok = in_sizes[0] / D_DIM;   // 16384

    size_t off_route = 256;
    size_t off_gate  = off_route + (size_t)ntok * 4;
    size_t off_lists = off_gate + (size_t)2 * ntok * 4;
    size_t off_xb    = off_lists + (size_t)NEXP * ntok * 4;
    size_t off_w1t   = off_xb + (size_t)ntok * D_DIM * 2;
    size_t off_w2t   = off_w1t + (size_t)NEXP * D_DIM * H_DIM * 2;
    size_t off_hdn   = off_w2t + (size_t)NEXP * D_DIM * H_DIM * 2;
    size_t need      = off_hdn + (size_t)(2 * ntok + 128) * H_DIM * 2;  // +slack rows

    int*   cb     = (int*)d_ws;
    int*   route  = (int*)((char*)d_ws + off_route);
    float* gate_w = (float*)((char*)d_ws + off_gate);
    int*   lists  = (int*)((char*)d_ws + off_lists);

    if (ws_size >= need) {
        unsigned short* xb  = (unsigned short*)((char*)d_ws + off_xb);
        unsigned short* W1T = (unsigned short*)((char*)d_ws + off_w1t);
        unsigned short* W2T = (unsigned short*)((char*)d_ws + off_w2t);
        unsigned short* hdn = (unsigned short*)((char*)d_ws + off_hdn);

        int n8 = ntok * D_DIM / 8;
        convert_x_kernel<<<(n8 + 255) / 256, 256, 0, stream>>>(x, xb, n8);
        transpose_conv_kernel<<<dim3(H_DIM / 64, D_DIM / 64, NEXP), 256, 0, stream>>>(
            W1, W1T, D_DIM, H_DIM);
        transpose_conv_kernel<<<dim3(D_DIM / 64, H_DIM / 64, NEXP), 256, 0, stream>>>(
            W2, W2T, H_DIM, D_DIM);
        router_kernel<<<(ntok + 3) / 4, 256, 0, stream>>>(
            x, Wr, gate_w, route, ntok);
        lists_kernel<<<NEXP, 256, 0, stream>>>(route, lists, cb, ntok);
        prefix_kernel<<<1, 64, 0, stream>>>(cb);
        bias_gate_kernel<<<(ntok + 3) / 4, 256, 0, stream>>>(
            route, gate_w, b2, out, ntok);
        int mtiles = ntok / 128;   // 128
        gemm1_kernel<<<NEXP * 16 * mtiles, 256, 0, stream>>>(
            xb, W1T, b1, gate_w, lists, cb, hdn, ntok);
        gemm2_kernel<<<NEXP * 4 * mtiles, 256, 0, stream>>>(
            hdn, W2T, lists, cb, out, ntok);
    } else {
        hipMemsetAsync(d_out, 0, (size_t)out_size * sizeof(float), stream);
        router_kernel<<<(ntok + 3) / 4, 256, 0, stream>>>(
            x, Wr, gate_w, route, ntok);
        lists_kernel<<<NEXP, 256, 0, stream>>>(route, lists, cb, ntok);
        prefix_kernel<<<1, 64, 0, stream>>>(cb);
        int tiles = (ntok + FBT - 1) / FBT;
        moe_fused_fallback<<<NEXP * tiles, FTPB, 0, stream>>>(
            x, W1, b1, W2, b2, gate_w, lists, cb, out, ntok, tiles);
    }
}

// Round 5
// 315.656 us; speedup vs baseline: 13.4971x; 1.1401x over previous
//
#include <hip/hip_runtime.h>
#include <math.h>

#define D_DIM 512
#define H_DIM 2048
#define NEXP  8

typedef __bf16 bf16x8 __attribute__((ext_vector_type(8)));
typedef float  f32x4  __attribute__((ext_vector_type(4)));

__device__ __forceinline__ unsigned short f2b(float f) {
    unsigned int u = __float_as_uint(f);
    unsigned int r = (u + 0x7FFFu + ((u >> 16) & 1u)) >> 16;
    return (unsigned short)r;
}

// exact-ish gelu: erf via Abramowitz-Stegun 7.1.26 (|err| < 1.5e-7)
__device__ __forceinline__ float gelu_f(float v) {
    float z = fabsf(v) * 0.70710678118654752440f;
    float t = __builtin_amdgcn_rcpf(fmaf(0.3275911f, z, 1.0f));
    float poly = t * (0.254829592f +
                 t * (-0.284496736f +
                 t * (1.421413741f +
                 t * (-1.453152027f +
                 t * 1.061405429f))));
    float er = 1.0f - poly * __expf(-z * z);
    er = (v < 0.0f) ? -er : er;
    return 0.5f * v * (1.0f + er);
}

__device__ __forceinline__ void async_cp16(const void* g, void* l) {
    __builtin_amdgcn_global_load_lds(
        (const __attribute__((address_space(1))) unsigned int*)g,
        (__attribute__((address_space(3))) unsigned int*)l, 16, 0, 0);
}

// in [e][R][C] f32 -> out [e][C][R] bf16
__global__ void transpose_conv_kernel(const float* __restrict__ in,
                                      unsigned short* __restrict__ out,
                                      int R, int C) {
    __shared__ unsigned short tile[64][72];
    int e = blockIdx.z;
    const float* ine = in + (size_t)e * R * C;
    unsigned short* oute = out + (size_t)e * C * R;
    int r0 = blockIdx.y * 64, c0 = blockIdx.x * 64;
    int tid = threadIdx.x;
#pragma unroll
    for (int rd = 0; rd < 4; ++rd) {
        int r = (tid >> 4) + rd * 16;
        int c = (tid & 15) * 4;
        float4 v = *(const float4*)&ine[(size_t)(r0 + r) * C + c0 + c];
        tile[c + 0][r] = f2b(v.x);
        tile[c + 1][r] = f2b(v.y);
        tile[c + 2][r] = f2b(v.z);
        tile[c + 3][r] = f2b(v.w);
    }
    __syncthreads();
    int cc = tid >> 2, rc = (tid & 3) * 16;
    unsigned short* op = oute + (size_t)(c0 + cc) * R + r0 + rc;
    *(uint4*)(op)     = *(const uint4*)&tile[cc][rc];
    *(uint4*)(op + 8) = *(const uint4*)&tile[cc][rc + 8];
}

// ---------------- router: top2+softmax + x->bf16 convert (NO atomics) ------
__global__ void router_kernel(const float* __restrict__ x,
                              const float* __restrict__ Wr,
                              float* __restrict__ gate_w,
                              int* __restrict__ route,
                              unsigned short* __restrict__ xbout,
                              int ntok) {
    int wid  = (blockIdx.x * blockDim.x + threadIdx.x) >> 6;
    int lane = threadIdx.x & 63;
    if (wid >= ntok) return;
    const float* xr = x + (size_t)wid * D_DIM;
    float acc[NEXP];
#pragma unroll
    for (int e = 0; e < NEXP; ++e) acc[e] = 0.0f;
#pragma unroll
    for (int it = 0; it < D_DIM / 64; ++it) {
        int d = it * 64 + lane;
        float xv = xr[d];
        if (xbout) xbout[(size_t)wid * D_DIM + d] = f2b(xv);
        const float* wr = Wr + d * NEXP;
#pragma unroll
        for (int e = 0; e < NEXP; ++e) acc[e] = fmaf(xv, wr[e], acc[e]);
    }
#pragma unroll
    for (int off = 32; off >= 1; off >>= 1) {
#pragma unroll
        for (int e = 0; e < NEXP; ++e) acc[e] += __shfl_xor(acc[e], off);
    }
    if (lane == 0) {
        int i0 = 0;
#pragma unroll
        for (int e = 1; e < NEXP; ++e) if (acc[e] > acc[i0]) i0 = e;
        int i1 = (i0 == 0) ? 1 : 0;
#pragma unroll
        for (int e = 0; e < NEXP; ++e) {
            if (e != i0 && acc[e] > acc[i1]) i1 = e;
        }
        float v0 = acc[i0], v1 = acc[i1];
        float ee = expf(v1 - v0);
        float inv = 1.0f / (1.0f + ee);
        int t = wid;
        gate_w[2 * t]     = inv;
        gate_w[2 * t + 1] = ee * inv;
        route[t] = i0 | (i1 << 8);
    }
}

// ---------------- deterministic per-expert stream compaction ---------------
__global__ void lists_kernel(const int* __restrict__ route,
                             int* __restrict__ lists,
                             int* __restrict__ cb,
                             int ntok) {
    __shared__ int wave_off[4];
    int e = blockIdx.x;
    int tid = threadIdx.x;
    int lane = tid & 63, w = tid >> 6;
    int running = 0;
    for (int c0 = 0; c0 < ntok; c0 += 256) {
        int t = c0 + tid;
        int rt = (t < ntok) ? route[t] : -1;
        int e0 = rt & 255, e1 = (rt >> 8) & 255;
        bool p1 = (e1 == e) && (rt >= 0);
        bool p  = ((e0 == e) && (rt >= 0)) || p1;
        unsigned long long mask = __ballot(p);
        int mypos = __popcll(mask & ((1ull << lane) - 1ull));
        int wcnt  = __popcll(mask);
        if (lane == 0) wave_off[w] = wcnt;
        __syncthreads();
        int wbase = 0;
#pragma unroll
        for (int i = 0; i < 4; ++i) if (i < w) wbase += wave_off[i];
        int total = wave_off[0] + wave_off[1] + wave_off[2] + wave_off[3];
        if (p) lists[(size_t)e * ntok + running + wbase + mypos] = 2 * t + (p1 ? 1 : 0);
        running += total;
        __syncthreads();
    }
    if (tid == 0) cb[e] = running;
}

__global__ void prefix_kernel(int* cb) {
    if (threadIdx.x == 0 && blockIdx.x == 0) {
        int s = 0;
#pragma unroll
        for (int e = 0; e < NEXP; ++e) { cb[8 + e] = s; s += cb[e]; }
    }
}

// out[tok] = w0*b2[e0] + w1*b2[e1]
__global__ void bias_gate_kernel(const int* __restrict__ route,
                                 const float* __restrict__ gate_w,
                                 const float* __restrict__ b2,
                                 float* __restrict__ out, int ntok) {
    int t = blockIdx.x * 4 + (threadIdx.x >> 6);
    int lane = threadIdx.x & 63;
    if (t >= ntok) return;
    int rt = route[t];
    int e0 = rt & 255, e1 = (rt >> 8) & 255;
    float w0 = gate_w[2 * t], w1 = gate_w[2 * t + 1];
    const float4* p0 = (const float4*)(b2 + (size_t)e0 * D_DIM);
    const float4* p1 = (const float4*)(b2 + (size_t)e1 * D_DIM);
    float4* po = (float4*)(out + (size_t)t * D_DIM);
#pragma unroll
    for (int j = 0; j < 2; ++j) {
        float4 a = p0[lane * 2 + j], b = p1[lane * 2 + j];
        float4 r;
        r.x = w0 * a.x + w1 * b.x;
        r.y = w0 * a.y + w1 * b.y;
        r.z = w0 * a.z + w1 * b.z;
        r.w = w0 * a.w + w1 * b.w;
        po[lane * 2 + j] = r;
    }
}

// ============ m97-style 128x128 BK=64 grouped GEMMs (SINGLE buffer) ========
// 4 waves (2Mx2N), wave tile 64x64 = acc[4][4] of 16x16x32 frags.
// A and B staged via global_load_lds w16 into ONE 32 KB tile (occupancy 4/CU);
// two barriers per K-step (m97 schedule). XOR swizzle: LDS row r holds global
// 16B-chunk (slot ^ (r&7)) at slot; read back with same XOR.

// ---------------- pass 1: hdn = gate * gelu(Xg @ W1T^T + b1) ---------------
__global__ __launch_bounds__(256, 4) void gemm1_kernel(
        const unsigned short* __restrict__ xb,    // [ntok][512] bf16
        const unsigned short* __restrict__ W1T,   // [E][2048][512] bf16
        const float* __restrict__ b1,             // [E][2048]
        const float* __restrict__ gate_w,
        const int* __restrict__ lists,
        const int* __restrict__ cb,               // counts[0..7] bases[8..15]
        unsigned short* __restrict__ hdn,         // [2*ntok+128][2048] bf16
        int ntok) {
    int bid = blockIdx.x;
    int e = bid & 7;                 // expert -> XCD pin
    int rest = bid >> 3;
    int ntile = rest & 15;           // 2048/128
    int mt = rest >> 4;
    int cnt = cb[e];
    if (mt * 128 >= cnt) return;
    int base = cb[8 + e];

    __shared__ unsigned short AsBs[16384];   // 32 KB: A tile 16K + B tile 16K
    __shared__ int   toksS[128];
    __shared__ float twS[128];
    unsigned short* As = AsBs;
    unsigned short* Bs = AsBs + 8192;

    int tid = threadIdx.x;
    int l = tid & 63, w = tid >> 6;
    int wm = (w & 1) * 64, wn = (w >> 1) * 64;

    if (tid < 128) {
        int idx = mt * 128 + tid;
        int entry = (idx < cnt) ? lists[(size_t)e * ntok + idx] : -1;
        toksS[tid] = (entry >= 0) ? (entry >> 1) : 0;
        twS[tid]   = (entry >= 0) ? gate_w[entry] : 0.0f;
    }
    __syncthreads();

    const char* Aglob[4];
    const char* Bglob[4];
    {
        int swz = ((l & 7) ^ (l >> 3)) * 16;
        const char* W1e = (const char*)(W1T + (size_t)e * H_DIM * D_DIM);
#pragma unroll
        for (int c = 0; c < 4; ++c) {
            int row = (w * 4 + c) * 8 + (l >> 3);       // row&7 == l>>3
            Aglob[c] = (const char*)xb + (size_t)toksS[row] * 1024 + swz;
            Bglob[c] = W1e + (size_t)(ntile * 128 + row) * 1024 + swz;
        }
    }

    f32x4 acc[4][4];
#pragma unroll
    for (int i = 0; i < 4; ++i)
#pragma unroll
        for (int j = 0; j < 4; ++j) acc[i][j] = (f32x4){0.f, 0.f, 0.f, 0.f};

    for (int kc = 0; kc < 8; ++kc) {
        __syncthreads();          // all waves done reading previous tile
        int ko = kc * 128;
#pragma unroll
        for (int c = 0; c < 4; ++c) {
            async_cp16(Aglob[c] + ko, (char*)As + (w * 4 + c) * 1024);
            async_cp16(Bglob[c] + ko, (char*)Bs + (w * 4 + c) * 1024);
        }
        __syncthreads();          // compiler drains vmcnt(0) before barrier
#pragma unroll
        for (int ks = 0; ks < 2; ++ks) {
            int g = ks * 4 + (l >> 4);
            bf16x8 av[4], bv[4];
#pragma unroll
            for (int mf = 0; mf < 4; ++mf) {
                int m = wm + mf * 16 + (l & 15);
                av[mf] = *(const bf16x8*)((const char*)As + m * 128 + ((g ^ (m & 7)) * 16));
            }
#pragma unroll
            for (int nf = 0; nf < 4; ++nf) {
                int n = wn + nf * 16 + (l & 15);
                bv[nf] = *(const bf16x8*)((const char*)Bs + n * 128 + ((g ^ (n & 7)) * 16));
            }
#pragma unroll
            for (int mf = 0; mf < 4; ++mf)
#pragma unroll
                for (int nf = 0; nf < 4; ++nf)
                    acc[mf][nf] = __builtin_amdgcn_mfma_f32_16x16x32_bf16(
                        av[mf], bv[nf], acc[mf][nf], 0, 0, 0);
        }
    }

    // ---- epilogue: gelu+gate -> LDS (swizzled) -> coalesced 16B stores ----
    float twr[4][4];
#pragma unroll
    for (int mf = 0; mf < 4; ++mf)
#pragma unroll
        for (int r = 0; r < 4; ++r)
            twr[mf][r] = twS[wm + mf * 16 + (l >> 4) * 4 + r];
    const float* b1e = b1 + (size_t)e * H_DIM + ntile * 128;
    float b1v[4];
#pragma unroll
    for (int nf = 0; nf < 4; ++nf)
        b1v[nf] = b1e[wn + nf * 16 + (l & 15)];

    __syncthreads();              // done reading As/Bs -> reuse as out tile
    char* Lo = (char*)AsBs;       // 32 KB out tile: [128 rows][256 B]
#pragma unroll
    for (int mf = 0; mf < 4; ++mf) {
#pragma unroll
        for (int nf = 0; nf < 4; ++nf) {
#pragma unroll
            for (int r = 0; r < 4; ++r) {
                int row = wm + mf * 16 + (l >> 4) * 4 + r;
                int col = wn + nf * 16 + (l & 15);
                float hv = twr[mf][r] * gelu_f(acc[mf][nf][r] + b1v[nf]);
                int byte = row * 256 + ((col * 2) ^ (((row >> 2) & 3) << 5));
                *(unsigned short*)(Lo + byte) = f2b(hv);
            }
        }
    }
    __syncthreads();
#pragma unroll
    for (int j = 0; j < 8; ++j) {
        int row = j * 16 + (tid >> 4);
        int c16 = tid & 15;
        uint4 v = *(const uint4*)(Lo + row * 256 + c16 * 16);
        int colchunk = c16 ^ (((row >> 2) & 3) << 1);
        int gr = mt * 128 + row;
        if (gr < cnt)
            *(uint4*)(hdn + (size_t)(base + gr) * H_DIM + ntile * 128 + colchunk * 8) = v;
    }
}

// ---------------- pass 2: out[tok] += hdn @ W2T^T --------------------------
__global__ __launch_bounds__(256, 4) void gemm2_kernel(
        const unsigned short* __restrict__ hdn,   // [2*ntok+128][2048] bf16
        const unsigned short* __restrict__ W2T,   // [E][512][2048] bf16
        const int* __restrict__ lists,
        const int* __restrict__ cb,
        float* __restrict__ out,
        int ntok) {
    int bid = blockIdx.x;
    int e = bid & 7;
    int rest = bid >> 3;
    int ntile = rest & 3;            // 512/128
    int mt = rest >> 2;
    int cnt = cb[e];
    if (mt * 128 >= cnt) return;
    int base = cb[8 + e];

    __shared__ unsigned short AsBs[16384];
    __shared__ int toksS[128];
    unsigned short* As = AsBs;
    unsigned short* Bs = AsBs + 8192;

    int tid = threadIdx.x;
    int l = tid & 63, w = tid >> 6;
    int wm = (w & 1) * 64, wn = (w >> 1) * 64;

    if (tid < 128) {
        int idx = mt * 128 + tid;
        int entry = (idx < cnt) ? lists[(size_t)e * ntok + idx] : -1;
        toksS[tid] = (entry >= 0) ? (entry >> 1) : 0;
    }
    __syncthreads();

    const char* Aglob[4];
    const char* Bglob[4];
    {
        int swz = ((l & 7) ^ (l >> 3)) * 16;
        const char* W2e = (const char*)(W2T + (size_t)e * D_DIM * H_DIM);
#pragma unroll
        for (int c = 0; c < 4; ++c) {
            int row = (w * 4 + c) * 8 + (l >> 3);
            Aglob[c] = (const char*)hdn + (size_t)(base + mt * 128 + row) * 4096 + swz;
            Bglob[c] = W2e + (size_t)(ntile * 128 + row) * 4096 + swz;
        }
    }

    f32x4 acc[4][4];
#pragma unroll
    for (int i = 0; i < 4; ++i)
#pragma unroll
        for (int j = 0; j < 4; ++j) acc[i][j] = (f32x4){0.f, 0.f, 0.f, 0.f};

    for (int kc = 0; kc < 32; ++kc) {
        __syncthreads();
        int ko = kc * 128;
#pragma unroll
        for (int c = 0; c < 4; ++c) {
            async_cp16(Aglob[c] + ko, (char*)As + (w * 4 + c) * 1024);
            async_cp16(Bglob[c] + ko, (char*)Bs + (w * 4 + c) * 1024);
        }
        __syncthreads();
#pragma unroll
        for (int ks = 0; ks < 2; ++ks) {
            int g = ks * 4 + (l >> 4);
            bf16x8 av[4], bv[4];
#pragma unroll
            for (int mf = 0; mf < 4; ++mf) {
                int m = wm + mf * 16 + (l & 15);
                av[mf] = *(const bf16x8*)((const char*)As + m * 128 + ((g ^ (m & 7)) * 16));
            }
#pragma unroll
            for (int nf = 0; nf < 4; ++nf) {
                int n = wn + nf * 16 + (l & 15);
                bv[nf] = *(const bf16x8*)((const char*)Bs + n * 128 + ((g ^ (n & 7)) * 16));
            }
#pragma unroll
            for (int mf = 0; mf < 4; ++mf)
#pragma unroll
                for (int nf = 0; nf < 4; ++nf)
                    acc[mf][nf] = __builtin_amdgcn_mfma_f32_16x16x32_bf16(
                        av[mf], bv[nf], acc[mf][nf], 0, 0, 0);
        }
    }

    // epilogue: masked atomic scatter (bias handled by bias_gate_kernel)
#pragma unroll
    for (int mf = 0; mf < 4; ++mf) {
#pragma unroll
        for (int r = 0; r < 4; ++r) {
            int rl = wm + mf * 16 + (l >> 4) * 4 + r;
            int gr = mt * 128 + rl;
            if (gr < cnt) {
                float* op = out + (size_t)toksS[rl] * D_DIM + ntile * 128 + wn;
#pragma unroll
                for (int nf = 0; nf < 4; ++nf)
                    atomicAdd(op + nf * 16 + (l & 15), acc[mf][nf][r]);
            }
        }
    }
}

// ================= fused fallback (small workspace) ========================
#define FBT 64
#define FKC 64
#define FHC 64
#define FTPB 512

__global__ __launch_bounds__(FTPB) void moe_fused_fallback(
        const float* __restrict__ x,
        const float* __restrict__ W1, const float* __restrict__ b1,
        const float* __restrict__ W2, const float* __restrict__ b2,
        const float* __restrict__ gate_w,
        const int* __restrict__ lists, const int* __restrict__ counts,
        float* __restrict__ out, int ntok, int tiles) {
    __shared__ __align__(16) float ldsA[FBT][FKC + 4];
    __shared__ __align__(16) float ldsB[FKC][FHC + 4];
    __shared__ int   toks[FBT];
    __shared__ float tw[FBT];
    int e = blockIdx.x / tiles;
    int tile = blockIdx.x % tiles;
    int cnt = counts[e];
    if (tile * FBT >= cnt) return;
    int tid = threadIdx.x;
    int srow = tid >> 3, scol = (tid & 7) * 8;
    int tg2 = tid >> 4, sg4 = tid & 15;
    if (tid < FBT) {
        int idx = tile * FBT + tid;
        int entry = (idx < cnt) ? lists[(size_t)e * ntok + idx] : -1;
        toks[tid] = (entry >= 0) ? (entry >> 1) : 0;
        tw[tid]   = (entry >= 0) ? gate_w[entry] : 0.0f;
    }
    __syncthreads();
    float yacc[2][32];
#pragma unroll
    for (int p = 0; p < 2; ++p)
#pragma unroll
        for (int i = 0; i < 32; ++i) yacc[p][i] = 0.0f;
    const float* W1e = W1 + (size_t)e * D_DIM * H_DIM;
    const float* W2e = W2 + (size_t)e * H_DIM * D_DIM;
    const float* b1e = b1 + (size_t)e * H_DIM;
    int t0 = tg2, t1 = tg2 + 32;
    for (int hc = 0; hc < H_DIM / FHC; ++hc) {
        float pre[2][4];
#pragma unroll
        for (int p = 0; p < 2; ++p)
#pragma unroll
            for (int j = 0; j < 4; ++j) pre[p][j] = 0.0f;
        for (int kc = 0; kc < D_DIM / FKC; ++kc) {
            __syncthreads();
            {
                const float* src = x + (size_t)toks[srow] * D_DIM + kc * FKC + scol;
                *(float4*)&ldsA[srow][scol]     = *(const float4*)(src);
                *(float4*)&ldsA[srow][scol + 4] = *(const float4*)(src + 4);
                const float* ws1 = W1e + (size_t)(kc * FKC + srow) * H_DIM + hc * FHC + scol;
                *(float4*)&ldsB[srow][scol]     = *(const float4*)(ws1);
                *(float4*)&ldsB[srow][scol + 4] = *(const float4*)(ws1 + 4);
            }
            __syncthreads();
#pragma unroll
            for (int k = 0; k < FKC; ++k) {
                float a0 = ldsA[t0][k], a1 = ldsA[t1][k];
                const float4 b4 = *(const float4*)&ldsB[k][sg4 * 4];
                pre[0][0] = fmaf(a0, b4.x, pre[0][0]);
                pre[0][1] = fmaf(a0, b4.y, pre[0][1]);
                pre[0][2] = fmaf(a0, b4.z, pre[0][2]);
                pre[0][3] = fmaf(a0, b4.w, pre[0][3]);
                pre[1][0] = fmaf(a1, b4.x, pre[1][0]);
                pre[1][1] = fmaf(a1, b4.y, pre[1][1]);
                pre[1][2] = fmaf(a1, b4.z, pre[1][2]);
                pre[1][3] = fmaf(a1, b4.w, pre[1][3]);
            }
        }
        __syncthreads();
        {
            const float* b1p = b1e + hc * FHC + sg4 * 4;
            float4 h0, h1;
            h0.x = gelu_f(pre[0][0] + b1p[0]); h0.y = gelu_f(pre[0][1] + b1p[1]);
            h0.z = gelu_f(pre[0][2] + b1p[2]); h0.w = gelu_f(pre[0][3] + b1p[3]);
            h1.x = gelu_f(pre[1][0] + b1p[0]); h1.y = gelu_f(pre[1][1] + b1p[1]);
            h1.z = gelu_f(pre[1][2] + b1p[2]); h1.w = gelu_f(pre[1][3] + b1p[3]);
            *(float4*)&ldsA[t0][sg4 * 4] = h0;
            *(float4*)&ldsA[t1][sg4 * 4] = h1;
        }
        for (int dt = 0; dt < 8; ++dt) {
            __syncthreads();
            {
                const float* ws2 = W2e + (size_t)(hc * FHC + srow) * D_DIM + dt * 64 + scol;
                *(float4*)&ldsB[srow][scol]     = *(const float4*)(ws2);
                *(float4*)&ldsB[srow][scol + 4] = *(const float4*)(ws2 + 4);
            }
            __syncthreads();
#pragma unroll
            for (int hh = 0; hh < FHC; ++hh) {
                float a0 = ldsA[t0][hh], a1 = ldsA[t1][hh];
                const float4 b4 = *(const float4*)&ldsB[hh][sg4 * 4];
                yacc[0][dt * 4 + 0] = fmaf(a0, b4.x, yacc[0][dt * 4 + 0]);
                yacc[0][dt * 4 + 1] = fmaf(a0, b4.y, yacc[0][dt * 4 + 1]);
                yacc[0][dt * 4 + 2] = fmaf(a0, b4.z, yacc[0][dt * 4 + 2]);
                yacc[0][dt * 4 + 3] = fmaf(a0, b4.w, yacc[0][dt * 4 + 3]);
                yacc[1][dt * 4 + 0] = fmaf(a1, b4.x, yacc[1][dt * 4 + 0]);
                yacc[1][dt * 4 + 1] = fmaf(a1, b4.y, yacc[1][dt * 4 + 1]);
                yacc[1][dt * 4 + 2] = fmaf(a1, b4.z, yacc[1][dt * 4 + 2]);
                yacc[1][dt * 4 + 3] = fmaf(a1, b4.w, yacc[1][dt * 4 + 3]);
            }
        }
    }
    const float* b2e = b2 + (size_t)e * D_DIM;
#pragma unroll
    for (int p = 0; p < 2; ++p) {
        int slot = (p == 0) ? t0 : t1;
        if (tile * FBT + slot < cnt) {
            float wv = tw[slot];
            float* op = out + (size_t)toks[slot] * D_DIM;
#pragma unroll
            for (int dt = 0; dt < 8; ++dt)
#pragma unroll
                for (int j = 0; j < 4; ++j) {
                    int d = dt * 64 + sg4 * 4 + j;
                    atomicAdd(&op[d], wv * (yacc[p][dt * 4 + j] + b2e[d]));
                }
        }
    }
}

// ===========================================================================
extern "C" void kernel_launch(void* const* d_in, const int* in_sizes, int n_in,
                              void* d_out, int out_size, void* d_ws, size_t ws_size,
                              hipStream_t stream) {
    const float* x  = (const float*)d_in[0];
    const float* Wr = (const float*)d_in[1];
    const float* W1 = (const float*)d_in[2];
    const float* b1 = (const float*)d_in[3];
    const float* W2 = (const float*)d_in[4];
    const float* b2 = (const float*)d_in[5];
    float* out = (float*)d_out;
    int ntok = in_sizes[0] / D_DIM;   // 16384

    size_t off_route = 256;
    size_t off_gate  = off_route + (size_t)ntok * 4;
    size_t off_lists = off_gate + (size_t)2 * ntok * 4;
    size_t off_xb    = off_lists + (size_t)NEXP * ntok * 4;
    size_t off_w1t   = off_xb + (size_t)ntok * D_DIM * 2;
    size_t off_w2t   = off_w1t + (size_t)NEXP * D_DIM * H_DIM * 2;
    size_t off_hdn   = off_w2t + (size_t)NEXP * D_DIM * H_DIM * 2;
    size_t need      = off_hdn + (size_t)(2 * ntok + 128) * H_DIM * 2;  // +slack rows

    int*   cb     = (int*)d_ws;
    int*   route  = (int*)((char*)d_ws + off_route);
    float* gate_w = (float*)((char*)d_ws + off_gate);
    int*   lists  = (int*)((char*)d_ws + off_lists);

    if (ws_size >= need) {
        unsigned short* xb  = (unsigned short*)((char*)d_ws + off_xb);
        unsigned short* W1T = (unsigned short*)((char*)d_ws + off_w1t);
        unsigned short* W2T = (unsigned short*)((char*)d_ws + off_w2t);
        unsigned short* hdn = (unsigned short*)((char*)d_ws + off_hdn);

        transpose_conv_kernel<<<dim3(H_DIM / 64, D_DIM / 64, NEXP), 256, 0, stream>>>(
            W1, W1T, D_DIM, H_DIM);
        transpose_conv_kernel<<<dim3(D_DIM / 64, H_DIM / 64, NEXP), 256, 0, stream>>>(
            W2, W2T, H_DIM, D_DIM);
        router_kernel<<<(ntok + 3) / 4, 256, 0, stream>>>(
            x, Wr, gate_w, route, xb, ntok);
        lists_kernel<<<NEXP, 256, 0, stream>>>(route, lists, cb, ntok);
        prefix_kernel<<<1, 64, 0, stream>>>(cb);
        bias_gate_kernel<<<(ntok + 3) / 4, 256, 0, stream>>>(
            route, gate_w, b2, out, ntok);
        int mtiles = ntok / 128;   // 128
        gemm1_kernel<<<NEXP * 16 * mtiles, 256, 0, stream>>>(
            xb, W1T, b1, gate_w, lists, cb, hdn, ntok);
        gemm2_kernel<<<NEXP * 4 * mtiles, 256, 0, stream>>>(
            hdn, W2T, lists, cb, out, ntok);
    } else {
        hipMemsetAsync(d_out, 0, (size_t)out_size * sizeof(float), stream);
        router_kernel<<<(ntok + 3) / 4, 256, 0, stream>>>(
            x, Wr, gate_w, route, (unsigned short*)0, ntok);
        lists_kernel<<<NEXP, 256, 0, stream>>>(route, lists, cb, ntok);
        prefix_kernel<<<1, 64, 0, stream>>>(cb);
        int tiles = (ntok + FBT - 1) / FBT;
        moe_fused_fallback<<<NEXP * tiles, FTPB, 0, stream>>>(
            x, W1, b1, W2, b2, gate_w, lists, cb, out, ntok, tiles);
    }
}